// Round 5
// baseline (6394.155 us; speedup 1.0000x reference)
//
#include <hip/hip_runtime.h>
#include <stdint.h>

#define NN 100000
#define RR 4
#define EE 1600000
#define DD 128
#define TN 32
#define BLK 256

// ------- scatter: agg[r][dst-n_lo] += feat[src][r], one wave/edge -------
__global__ __launch_bounds__(256)
void k_scatter(const float* __restrict__ nf, const int* __restrict__ src,
               const int* __restrict__ dst, float* __restrict__ agg,
               int n_lo, int n_hi, int chunkN) {
  const int r = blockIdx.y;
  const long gw = (((long)blockIdx.x * 256) + threadIdx.x) >> 6;
  const int lane = threadIdx.x & 63;
  if (gw >= EE) return;
  const int d = dst[(size_t)r * EE + gw];
  if (d < n_lo || d >= n_hi) return;  // wave-uniform
  const int s = src[(size_t)r * EE + gw];
  const float2 v = *(const float2*)(nf + ((size_t)s * RR + r) * DD + lane * 2);
  float* o = agg + ((size_t)r * chunkN + (d - n_lo)) * DD + lane * 2;
  atomicAdd(o,     v.x);
  atomicAdd(o + 1, v.y);
}

// ---- copy one 64-row half of a 128x128 f32 weight into LDS ----
__device__ __forceinline__ void loadWh(const float* __restrict__ Wsrc, int half,
                                       float* __restrict__ sW, int tid) {
  const float4* src = (const float4*)(Wsrc + (size_t)half * 64 * DD);
  float4* dstv = (float4*)sW;
#pragma unroll
  for (int k = 0; k < 8; ++k) dstv[tid + k * BLK] = src[tid + k * BLK];  // 2048 float4
}

// ---- half-K gemm: acc[ii] += sum_{d in [0,64)} A[row][kbase+d] * W[d][j] ----
__device__ __forceinline__ void gemm_half(const float (*__restrict__ in)[DD],
                                          const float* __restrict__ sW,
                                          int j, int g, int kbase, float* acc) {
  for (int d4 = 0; d4 < 64; d4 += 4) {
    const float w0 = sW[(d4 + 0) * DD + j];
    const float w1 = sW[(d4 + 1) * DD + j];
    const float w2 = sW[(d4 + 2) * DD + j];
    const float w3 = sW[(d4 + 3) * DD + j];
#pragma unroll
    for (int ii = 0; ii < 16; ++ii) {
      const float4 a = *(const float4*)(&in[g + ii * 2][kbase + d4]);
      acc[ii] = fmaf(a.x, w0, fmaf(a.y, w1, fmaf(a.z, w2, fmaf(a.w, w3, acc[ii]))));
    }
  }
}

// ---------------- fused MLP + LN + attention scores ----------------
__global__ __launch_bounds__(BLK)
void k_mlp(const float* __restrict__ nf, const float* __restrict__ W1, const float* __restrict__ b1,
           const float* __restrict__ W2, const float* __restrict__ b2,
           const float* __restrict__ Ws1, const float* __restrict__ Ws2,
           const float* __restrict__ gamma, const float* __restrict__ beta,
           const float* __restrict__ agg, float* __restrict__ S,
           float* __restrict__ out, int n_lo, int n_hi, int chunkN) {
  __shared__ float sA[TN][DD];                 // 16 KB
  __shared__ __align__(16) float sW[64 * DD];  // 32 KB  (total 48 KB)

  const int tid = threadIdx.x;
  const int r = blockIdx.y;
  const int n0 = n_lo + blockIdx.x * TN;
  const int j = tid & 127;
  const int g = tid >> 7;  // 0..1

  // ---- stage rst = feat + agg -> sA ----
  for (int idx = tid; idx < TN * DD / 2; idx += BLK) {  // 2048 float2
    const int i = idx >> 6;
    const int c = (idx & 63) * 2;
    const int n = n0 + i;
    float2 v = make_float2(0.f, 0.f);
    if (n < n_hi) {
      const float2 f = *(const float2*)(nf + ((size_t)n * RR + r) * DD + c);
      const float2 a = *(const float2*)(agg + ((size_t)r * chunkN + (n - n_lo)) * DD + c);
      v.x = f.x + a.x;
      v.y = f.y + a.y;
    }
    *(float2*)(&sA[i][c]) = v;
  }
  loadWh(W1, 0, sW, tid);
  __syncthreads();

  float acc[16];
#pragma unroll
  for (int ii = 0; ii < 16; ++ii) acc[ii] = 0.f;

  // ---- GEMM1 ----
  gemm_half(sA, sW, j, g, 0, acc);
  __syncthreads();
  loadWh(W1, 1, sW, tid);
  __syncthreads();
  gemm_half(sA, sW, j, g, 64, acc);
  __syncthreads();
  {
    const float bb = b1[j];
#pragma unroll
    for (int ii = 0; ii < 16; ++ii) sA[g + ii * 2][j] = fmaxf(acc[ii] + bb, 0.f);
  }
  loadWh(W2, 0, sW, tid);
  __syncthreads();

  // ---- GEMM2 ----
#pragma unroll
  for (int ii = 0; ii < 16; ++ii) acc[ii] = 0.f;
  gemm_half(sA, sW, j, g, 0, acc);
  __syncthreads();
  loadWh(W2, 1, sW, tid);
  __syncthreads();
  gemm_half(sA, sW, j, g, 64, acc);
  __syncthreads();
  {
    const float bb = b2[j];
#pragma unroll
    for (int ii = 0; ii < 16; ++ii) sA[g + ii * 2][j] = fmaxf(acc[ii] + bb, 0.f);
  }
  loadWh(Ws1 + (size_t)r * DD * DD, 0, sW, tid);
  __syncthreads();

  // ---- LayerNorm (8 threads/row, stats in registers via shfl) ----
  {
    const int i = tid >> 3;          // 0..31
    const int c0 = (tid & 7) * 16;
    float s = 0.f, s2 = 0.f;
    float hv[16];
#pragma unroll
    for (int c = 0; c < 16; ++c) {
      const float v = sA[i][c0 + c];
      hv[c] = v;
      s += v; s2 += v * v;
    }
#pragma unroll
    for (int off = 1; off < 8; off <<= 1) {
      s  += __shfl_xor(s, off);
      s2 += __shfl_xor(s2, off);
    }
    const float mu = s * (1.f / 128.f);
    const float var = fmaxf(s2 * (1.f / 128.f) - mu * mu, 0.f);
    const float rs = rsqrtf(var + 1e-5f);
    const int n = n0 + i;
#pragma unroll
    for (int c = 0; c < 16; ++c) {
      hv[c] = (hv[c] - mu) * rs * gamma[c0 + c] + beta[c0 + c];
      sA[i][c0 + c] = hv[c];   // own slice only: no cross-thread hazard
    }
    if (n < n_hi) {
      float4* op = (float4*)(out + ((size_t)n * RR + r) * DD + c0);
#pragma unroll
      for (int q = 0; q < 4; ++q)
        op[q] = make_float4(hv[q * 4], hv[q * 4 + 1], hv[q * 4 + 2], hv[q * 4 + 3]);
    }
  }
  __syncthreads();

  // ---- GEMM3: tanh(h @ Ws1[r]) ----
#pragma unroll
  for (int ii = 0; ii < 16; ++ii) acc[ii] = 0.f;
  gemm_half(sA, sW, j, g, 0, acc);
  __syncthreads();
  loadWh(Ws1 + (size_t)r * DD * DD, 1, sW, tid);
  __syncthreads();
  gemm_half(sA, sW, j, g, 64, acc);
  __syncthreads();
#pragma unroll
  for (int ii = 0; ii < 16; ++ii) sA[g + ii * 2][j] = tanhf(acc[ii]);
  {
    sW[tid]       = Ws2[(size_t)r * 512 + tid];
    sW[tid + 256] = Ws2[(size_t)r * 512 + tid + 256];
  }
  __syncthreads();

  // ---- scores = tanh(...) @ Ws2[r] -> S (chunk-local layout) ----
  if (tid < TN * 4) {
    const int i = tid >> 2;
    const int k = tid & 3;
    float a = 0.f;
#pragma unroll 8
    for (int q = 0; q < DD; ++q) a = fmaf(sA[i][q], sW[q * 4 + k], a);
    const int n = n0 + i;
    if (n < n_hi) S[((size_t)r * chunkN + (n - n_lo)) * 4 + k] = a;
  }
}

// -------- softmax over relations + final mix (in place on out) --------
__global__ __launch_bounds__(256)
void k_combine(const float* __restrict__ S, float* __restrict__ out,
               int n_lo, int n_hi, int chunkN) {
  const long gw = (((long)blockIdx.x * 256) + threadIdx.x) >> 6;
  const int lane = threadIdx.x & 63;
  if (gw >= chunkN) return;
  const int n = n_lo + (int)gw;
  if (n >= n_hi) return;
  float a[4][4];
#pragma unroll
  for (int r = 0; r < 4; ++r)
#pragma unroll
    for (int k = 0; k < 4; ++k)
      a[r][k] = S[((size_t)r * chunkN + gw) * 4 + k];
#pragma unroll
  for (int k = 0; k < 4; ++k) {
    const float m = fmaxf(fmaxf(a[0][k], a[1][k]), fmaxf(a[2][k], a[3][k]));
    const float e0 = expf(a[0][k] - m);
    const float e1 = expf(a[1][k] - m);
    const float e2 = expf(a[2][k] - m);
    const float e3 = expf(a[3][k] - m);
    const float inv = 1.f / (e0 + e1 + e2 + e3);
    a[0][k] = e0 * inv; a[1][k] = e1 * inv; a[2][k] = e2 * inv; a[3][k] = e3 * inv;
  }
  float2 hv[4];
#pragma unroll
  for (int k = 0; k < 4; ++k)
    hv[k] = *(const float2*)(out + ((size_t)n * RR + k) * DD + lane * 2);
#pragma unroll
  for (int r = 0; r < 4; ++r) {
    float2 o;
    o.x = a[r][0] * hv[0].x + a[r][1] * hv[1].x + a[r][2] * hv[2].x + a[r][3] * hv[3].x;
    o.y = a[r][0] * hv[0].y + a[r][1] * hv[1].y + a[r][2] * hv[2].y + a[r][3] * hv[3].y;
    *(float2*)(out + ((size_t)n * RR + r) * DD + lane * 2) = o;
  }
}

extern "C" void kernel_launch(void* const* d_in, const int* in_sizes, int n_in,
                              void* d_out, int out_size, void* d_ws, size_t ws_size,
                              hipStream_t stream) {
  const float* nf    = (const float*)d_in[0];
  const int*   src   = (const int*)d_in[1];
  const int*   dst   = (const int*)d_in[2];
  const float* W1    = (const float*)d_in[3];
  const float* b1    = (const float*)d_in[4];
  const float* W2    = (const float*)d_in[5];
  const float* b2    = (const float*)d_in[6];
  const float* Ws1   = (const float*)d_in[7];
  const float* Ws2   = (const float*)d_in[8];
  const float* gamma = (const float*)d_in[9];
  const float* beta  = (const float*)d_in[10];
  float* out = (float*)d_out;

  // per-node ws: agg 4*128*4B + S 4*4*4B = 2112 B
  const size_t perNode = (size_t)RR * DD * 4 + (size_t)RR * 4 * 4;
  long chunk = (ws_size >= perNode * 32) ? (long)(ws_size / perNode) : 32;
  if (chunk > NN) chunk = NN;
  chunk &= ~31L;
  if (chunk < 32) chunk = 32;

  for (long n_lo = 0; n_lo < NN; n_lo += chunk) {
    const long n_hi = (n_lo + chunk < NN) ? (n_lo + chunk) : NN;
    const int cn = (int)(n_hi - n_lo);
    float* agg = (float*)d_ws;
    float* S   = agg + (size_t)RR * cn * DD;

    hipMemsetAsync(d_ws, 0, (size_t)cn * perNode, stream);  // zeros agg AND S
    {
      dim3 grid((unsigned)((EE + 3) / 4), RR);  // 1 wave/edge, 4 waves/block
      k_scatter<<<grid, dim3(256), 0, stream>>>(nf, src, dst, agg,
                                                (int)n_lo, (int)n_hi, cn);
    }
    {
      dim3 grid((unsigned)((cn + TN - 1) / TN), RR);
      k_mlp<<<grid, dim3(BLK), 0, stream>>>(nf, W1, b1, W2, b2, Ws1, Ws2,
                                            gamma, beta, agg, S, out,
                                            (int)n_lo, (int)n_hi, cn);
    }
    {
      const long blocks = ((long)cn + 3) / 4;  // 1 wave/node
      k_combine<<<dim3((unsigned)blocks), dim3(256), 0, stream>>>(
          S, out, (int)n_lo, (int)n_hi, cn);
    }
  }
}

// Round 6
// 2729.562 us; speedup vs baseline: 2.3426x; 2.3426x over previous
//
#include <hip/hip_runtime.h>
#include <stdint.h>

#define NN 100000
#define RR 4
#define EE 1600000
#define DD 128
#define TN 32
#define BLK 256

// ---------- pass 1: histogram of dst (offsets shifted by +1) ----------
__global__ __launch_bounds__(256)
void k_hist(const int* __restrict__ dst, int* __restrict__ off) {
  const int r = blockIdx.y;
  const long e = (long)blockIdx.x * 256 + threadIdx.x;
  if (e >= EE) return;
  const int d = dst[(size_t)r * EE + e];
  atomicAdd(&off[(size_t)r * (NN + 1) + d + 1], 1);
}

// ---------- pass 2: inclusive scan over off[r][0..NN] (one block/rel) ----------
__global__ __launch_bounds__(1024)
void k_scan(int* __restrict__ off, int* __restrict__ cursor) {
  const int r = blockIdx.x;
  int* a = off + (size_t)r * (NN + 1);
  __shared__ int tmp[1024];
  const int t = threadIdx.x;
  int carry = 0;
  for (int base = 0; base < NN + 1; base += 1024) {
    const int idx = base + t;
    tmp[t] = (idx <= NN) ? a[idx] : 0;
    __syncthreads();
    for (int o = 1; o < 1024; o <<= 1) {
      const int y = (t >= o) ? tmp[t - o] : 0;
      __syncthreads();
      tmp[t] += y;
      __syncthreads();
    }
    const int inc = tmp[t] + carry;
    if (idx <= NN) a[idx] = inc;
    if (idx < NN) cursor[(size_t)r * NN + idx] = inc;
    carry += tmp[1023];
    __syncthreads();
  }
}

// ---------- pass 3: counting-sort fill of sortedSrc ----------
__global__ __launch_bounds__(256)
void k_fill(const int* __restrict__ src, const int* __restrict__ dst,
            int* __restrict__ cursor, int* __restrict__ sortedSrc) {
  const int r = blockIdx.y;
  const long e = (long)blockIdx.x * 256 + threadIdx.x;
  if (e >= EE) return;
  const int d = dst[(size_t)r * EE + e];
  const int pos = atomicAdd(&cursor[(size_t)r * NN + d], 1);
  sortedSrc[(size_t)r * EE + pos] = src[(size_t)r * EE + e];
}

// ---- copy one 64-row half of a 128x128 f32 weight into LDS ----
__device__ __forceinline__ void loadWh(const float* __restrict__ Wsrc, int half,
                                       float* __restrict__ sW, int tid) {
  const float4* src = (const float4*)(Wsrc + (size_t)half * 64 * DD);
  float4* dstv = (float4*)sW;
#pragma unroll
  for (int k = 0; k < 8; ++k) dstv[tid + k * BLK] = src[tid + k * BLK];  // 2048 float4
}

// ---- half-K gemm: acc[ii] += sum_{d in [0,64)} A[row][kbase+d] * W[d][j] ----
__device__ __forceinline__ void gemm_half(const float (*__restrict__ in)[DD],
                                          const float* __restrict__ sW,
                                          int j, int g, int kbase, float* acc) {
  for (int d4 = 0; d4 < 64; d4 += 4) {
    const float w0 = sW[(d4 + 0) * DD + j];
    const float w1 = sW[(d4 + 1) * DD + j];
    const float w2 = sW[(d4 + 2) * DD + j];
    const float w3 = sW[(d4 + 3) * DD + j];
#pragma unroll
    for (int ii = 0; ii < 16; ++ii) {
      const float4 a = *(const float4*)(&in[g + ii * 2][kbase + d4]);
      acc[ii] = fmaf(a.x, w0, fmaf(a.y, w1, fmaf(a.z, w2, fmaf(a.w, w3, acc[ii]))));
    }
  }
}

// ------- fused: gather(CSR) + residual + MLP + LN + attention scores -------
__global__ __launch_bounds__(BLK)
void k_mlp(const float* __restrict__ nf, const float* __restrict__ W1, const float* __restrict__ b1,
           const float* __restrict__ W2, const float* __restrict__ b2,
           const float* __restrict__ Ws1, const float* __restrict__ Ws2,
           const float* __restrict__ gamma, const float* __restrict__ beta,
           const int* __restrict__ off, const int* __restrict__ sortedSrc,
           float* __restrict__ S, float* __restrict__ out) {
  __shared__ float sA[TN][DD];                 // 16 KB
  __shared__ __align__(16) float sW[64 * DD];  // 32 KB  (total 48 KB)

  const int tid = threadIdx.x;
  const int r = blockIdx.y;
  const int n0 = blockIdx.x * TN;
  const int j = tid & 127;
  const int g = tid >> 7;  // 0..1

  // ---- stage rst = feat + gather(CSR) -> sA; each wave owns 8 rows ----
  {
    const int wv = tid >> 6;
    const int lane = tid & 63;
    const int* ss = sortedSrc + (size_t)r * EE;
#pragma unroll
    for (int q = 0; q < 8; ++q) {
      const int i = wv * 8 + q;
      const int n = n0 + i;
      float2 acc2 = make_float2(0.f, 0.f);
      if (n < NN) {
        acc2 = *(const float2*)(nf + ((size_t)n * RR + r) * DD + lane * 2);
        const int e1 = off[(size_t)r * (NN + 1) + n + 1];
        int e = off[(size_t)r * (NN + 1) + n];
        for (; e + 1 < e1; e += 2) {  // unroll-2 for load ILP
          const int s0 = ss[e], s1 = ss[e + 1];
          const float2 v0 = *(const float2*)(nf + ((size_t)s0 * RR + r) * DD + lane * 2);
          const float2 v1 = *(const float2*)(nf + ((size_t)s1 * RR + r) * DD + lane * 2);
          acc2.x += v0.x + v1.x;
          acc2.y += v0.y + v1.y;
        }
        if (e < e1) {
          const int s0 = ss[e];
          const float2 v0 = *(const float2*)(nf + ((size_t)s0 * RR + r) * DD + lane * 2);
          acc2.x += v0.x;
          acc2.y += v0.y;
        }
      }
      *(float2*)(&sA[i][lane * 2]) = acc2;
    }
  }
  loadWh(W1, 0, sW, tid);
  __syncthreads();

  float acc[16];
#pragma unroll
  for (int ii = 0; ii < 16; ++ii) acc[ii] = 0.f;

  // ---- GEMM1 ----
  gemm_half(sA, sW, j, g, 0, acc);
  __syncthreads();
  loadWh(W1, 1, sW, tid);
  __syncthreads();
  gemm_half(sA, sW, j, g, 64, acc);
  __syncthreads();
  {
    const float bb = b1[j];
#pragma unroll
    for (int ii = 0; ii < 16; ++ii) sA[g + ii * 2][j] = fmaxf(acc[ii] + bb, 0.f);
  }
  loadWh(W2, 0, sW, tid);
  __syncthreads();

  // ---- GEMM2 ----
#pragma unroll
  for (int ii = 0; ii < 16; ++ii) acc[ii] = 0.f;
  gemm_half(sA, sW, j, g, 0, acc);
  __syncthreads();
  loadWh(W2, 1, sW, tid);
  __syncthreads();
  gemm_half(sA, sW, j, g, 64, acc);
  __syncthreads();
  {
    const float bb = b2[j];
#pragma unroll
    for (int ii = 0; ii < 16; ++ii) sA[g + ii * 2][j] = fmaxf(acc[ii] + bb, 0.f);
  }
  loadWh(Ws1 + (size_t)r * DD * DD, 0, sW, tid);
  __syncthreads();

  // ---- LayerNorm (8 threads/row, stats in registers via shfl) ----
  {
    const int i = tid >> 3;          // 0..31
    const int c0 = (tid & 7) * 16;
    float s = 0.f, s2 = 0.f;
    float hv[16];
#pragma unroll
    for (int c = 0; c < 16; ++c) {
      const float v = sA[i][c0 + c];
      hv[c] = v;
      s += v; s2 += v * v;
    }
#pragma unroll
    for (int off2 = 1; off2 < 8; off2 <<= 1) {
      s  += __shfl_xor(s, off2);
      s2 += __shfl_xor(s2, off2);
    }
    const float mu = s * (1.f / 128.f);
    const float var = fmaxf(s2 * (1.f / 128.f) - mu * mu, 0.f);
    const float rs = rsqrtf(var + 1e-5f);
    const int n = n0 + i;
#pragma unroll
    for (int c = 0; c < 16; ++c) {
      hv[c] = (hv[c] - mu) * rs * gamma[c0 + c] + beta[c0 + c];
      sA[i][c0 + c] = hv[c];   // own slice only: no cross-thread hazard
    }
    if (n < NN) {
      float4* op = (float4*)(out + ((size_t)n * RR + r) * DD + c0);
#pragma unroll
      for (int q = 0; q < 4; ++q)
        op[q] = make_float4(hv[q * 4], hv[q * 4 + 1], hv[q * 4 + 2], hv[q * 4 + 3]);
    }
  }
  __syncthreads();

  // ---- GEMM3: tanh(h @ Ws1[r]) ----
#pragma unroll
  for (int ii = 0; ii < 16; ++ii) acc[ii] = 0.f;
  gemm_half(sA, sW, j, g, 0, acc);
  __syncthreads();
  loadWh(Ws1 + (size_t)r * DD * DD, 1, sW, tid);
  __syncthreads();
  gemm_half(sA, sW, j, g, 64, acc);
  __syncthreads();
#pragma unroll
  for (int ii = 0; ii < 16; ++ii) sA[g + ii * 2][j] = tanhf(acc[ii]);
  {
    sW[tid]       = Ws2[(size_t)r * 512 + tid];
    sW[tid + 256] = Ws2[(size_t)r * 512 + tid + 256];
  }
  __syncthreads();

  // ---- scores = tanh(...) @ Ws2[r] -> S ----
  if (tid < TN * 4) {
    const int i = tid >> 2;
    const int k = tid & 3;
    float a = 0.f;
#pragma unroll 8
    for (int q = 0; q < DD; ++q) a = fmaf(sA[i][q], sW[q * 4 + k], a);
    const int n = n0 + i;
    if (n < NN) S[((size_t)r * NN + n) * 4 + k] = a;
  }
}

// -------- softmax over relations + final mix (in place on out) --------
__global__ __launch_bounds__(256)
void k_combine(const float* __restrict__ S, float* __restrict__ out) {
  const long gw = (((long)blockIdx.x * 256) + threadIdx.x) >> 6;
  const int lane = threadIdx.x & 63;
  if (gw >= NN) return;
  const int n = (int)gw;
  float a[4][4];
#pragma unroll
  for (int r = 0; r < 4; ++r)
#pragma unroll
    for (int k = 0; k < 4; ++k)
      a[r][k] = S[((size_t)r * NN + n) * 4 + k];
#pragma unroll
  for (int k = 0; k < 4; ++k) {
    const float m = fmaxf(fmaxf(a[0][k], a[1][k]), fmaxf(a[2][k], a[3][k]));
    const float e0 = expf(a[0][k] - m);
    const float e1 = expf(a[1][k] - m);
    const float e2 = expf(a[2][k] - m);
    const float e3 = expf(a[3][k] - m);
    const float inv = 1.f / (e0 + e1 + e2 + e3);
    a[0][k] = e0 * inv; a[1][k] = e1 * inv; a[2][k] = e2 * inv; a[3][k] = e3 * inv;
  }
  float2 hv[4];
#pragma unroll
  for (int k = 0; k < 4; ++k)
    hv[k] = *(const float2*)(out + ((size_t)n * RR + k) * DD + lane * 2);
#pragma unroll
  for (int r = 0; r < 4; ++r) {
    float2 o;
    o.x = a[r][0] * hv[0].x + a[r][1] * hv[1].x + a[r][2] * hv[2].x + a[r][3] * hv[3].x;
    o.y = a[r][0] * hv[0].y + a[r][1] * hv[1].y + a[r][2] * hv[2].y + a[r][3] * hv[3].y;
    *(float2*)(out + ((size_t)n * RR + r) * DD + lane * 2) = o;
  }
}

extern "C" void kernel_launch(void* const* d_in, const int* in_sizes, int n_in,
                              void* d_out, int out_size, void* d_ws, size_t ws_size,
                              hipStream_t stream) {
  const float* nf    = (const float*)d_in[0];
  const int*   src   = (const int*)d_in[1];
  const int*   dst   = (const int*)d_in[2];
  const float* W1    = (const float*)d_in[3];
  const float* b1    = (const float*)d_in[4];
  const float* W2    = (const float*)d_in[5];
  const float* b2    = (const float*)d_in[6];
  const float* Ws1   = (const float*)d_in[7];
  const float* Ws2   = (const float*)d_in[8];
  const float* gamma = (const float*)d_in[9];
  const float* beta  = (const float*)d_in[10];
  float* out = (float*)d_out;

  // ws layout (~35.2 MB; round-5 behavior proved ws_size >= 211 MB):
  //   S       : RR*NN*4 f32   (6.4 MB)
  //   off     : RR*(NN+1) int (1.6 MB)   CSR offsets (exclusive)
  //   cursor  : RR*NN int     (1.6 MB)   fill cursors
  //   sorted  : RR*EE int     (25.6 MB)  src indices grouped by dst
  float* S      = (float*)d_ws;
  int*   off    = (int*)(S + (size_t)RR * NN * 4);
  int*   cursor = off + (size_t)RR * (NN + 1);
  int*   sorted = cursor + (size_t)RR * NN;

  hipMemsetAsync(off, 0, (size_t)RR * (NN + 1) * sizeof(int), stream);
  {
    dim3 grid((EE + 255) / 256, RR);
    k_hist<<<grid, dim3(256), 0, stream>>>(dst, off);
  }
  k_scan<<<dim3(RR), dim3(1024), 0, stream>>>(off, cursor);
  {
    dim3 grid((EE + 255) / 256, RR);
    k_fill<<<grid, dim3(256), 0, stream>>>(src, dst, cursor, sorted);
  }
  {
    dim3 grid((NN + TN - 1) / TN, RR);
    k_mlp<<<grid, dim3(BLK), 0, stream>>>(nf, W1, b1, W2, b2, Ws1, Ws2,
                                          gamma, beta, off, sorted, S, out);
  }
  {
    const long blocks = ((long)NN + 3) / 4;  // 1 wave/node
    k_combine<<<dim3((unsigned)blocks), dim3(256), 0, stream>>>(S, out);
  }
}

// Round 7
// 2551.617 us; speedup vs baseline: 2.5059x; 1.0697x over previous
//
#include <hip/hip_runtime.h>
#include <stdint.h>

#define NN 100000
#define RR 4
#define EE 1600000
#define DD 128
#define TN 32
#define BLK 256
#define NB 98  // ceil((NN+1)/1024)

// ---------- pass 1: histogram of dst (offsets shifted by +1) ----------
__global__ __launch_bounds__(256)
void k_hist(const int* __restrict__ dst, int* __restrict__ off) {
  const int r = blockIdx.y;
  const long e = (long)blockIdx.x * 256 + threadIdx.x;
  if (e >= EE) return;
  const int d = dst[(size_t)r * EE + e];
  atomicAdd(&off[(size_t)r * (NN + 1) + d + 1], 1);
}

// ---------- pass 2a: block-local inclusive scan ----------
__global__ __launch_bounds__(1024)
void k_scan1(int* __restrict__ off, int* __restrict__ bsum) {
  const int r = blockIdx.y;
  int* a = off + (size_t)r * (NN + 1);
  __shared__ int tmp[1024];
  const int t = threadIdx.x;
  const int idx = blockIdx.x * 1024 + t;
  tmp[t] = (idx <= NN) ? a[idx] : 0;
  __syncthreads();
  for (int o = 1; o < 1024; o <<= 1) {
    const int y = (t >= o) ? tmp[t - o] : 0;
    __syncthreads();
    tmp[t] += y;
    __syncthreads();
  }
  if (idx <= NN) a[idx] = tmp[t];
  if (t == 1023) bsum[r * NB + blockIdx.x] = tmp[1023];
}

// ---------- pass 2b: scan the 98 block sums -> exclusive prefix ----------
__global__ __launch_bounds__(128)
void k_scan2(int* __restrict__ bsum) {
  const int r = blockIdx.x;
  __shared__ int tmp[128];
  const int t = threadIdx.x;
  const int v = (t < NB) ? bsum[r * NB + t] : 0;
  tmp[t] = v;
  __syncthreads();
  for (int o = 1; o < 128; o <<= 1) {
    const int y = (t >= o) ? tmp[t - o] : 0;
    __syncthreads();
    tmp[t] += y;
    __syncthreads();
  }
  if (t < NB) bsum[r * NB + t] = tmp[t] - v;  // exclusive
}

// ---------- pass 2c: add block prefix; emit cursor copy ----------
__global__ __launch_bounds__(1024)
void k_scan3(int* __restrict__ off, const int* __restrict__ bsum,
             int* __restrict__ cursor) {
  const int r = blockIdx.y;
  const int idx = blockIdx.x * 1024 + threadIdx.x;
  const int add = bsum[r * NB + blockIdx.x];
  int* a = off + (size_t)r * (NN + 1);
  if (idx <= NN) {
    const int v = a[idx] + add;
    a[idx] = v;
    if (idx < NN) cursor[(size_t)r * NN + idx] = v;
  }
}

// ---------- pass 3: counting-sort fill of sortedSrc ----------
__global__ __launch_bounds__(256)
void k_fill(const int* __restrict__ src, const int* __restrict__ dst,
            int* __restrict__ cursor, int* __restrict__ sortedSrc) {
  const int r = blockIdx.y;
  const long e = (long)blockIdx.x * 256 + threadIdx.x;
  if (e >= EE) return;
  const int d = dst[(size_t)r * EE + e];
  const int pos = atomicAdd(&cursor[(size_t)r * NN + d], 1);
  sortedSrc[(size_t)r * EE + pos] = src[(size_t)r * EE + e];
}

// ---- copy one 64-row half of a 128x128 f32 weight into LDS ----
__device__ __forceinline__ void loadWh(const float* __restrict__ Wsrc, int half,
                                       float* __restrict__ sW, int tid) {
  const float4* src = (const float4*)(Wsrc + (size_t)half * 64 * DD);
  float4* dstv = (float4*)sW;
#pragma unroll
  for (int k = 0; k < 8; ++k) dstv[tid + k * BLK] = src[tid + k * BLK];  // 2048 float4
}

// ---- half-K gemm: acc[ii] += sum_{d in [0,64)} A[row][kbase+d] * W[d][j] ----
__device__ __forceinline__ void gemm_half(const float (*__restrict__ in)[DD],
                                          const float* __restrict__ sW,
                                          int j, int g, int kbase, float* acc) {
  for (int d4 = 0; d4 < 64; d4 += 4) {
    const float w0 = sW[(d4 + 0) * DD + j];
    const float w1 = sW[(d4 + 1) * DD + j];
    const float w2 = sW[(d4 + 2) * DD + j];
    const float w3 = sW[(d4 + 3) * DD + j];
#pragma unroll
    for (int ii = 0; ii < 16; ++ii) {
      const float4 a = *(const float4*)(&in[g + ii * 2][kbase + d4]);
      acc[ii] = fmaf(a.x, w0, fmaf(a.y, w1, fmaf(a.z, w2, fmaf(a.w, w3, acc[ii]))));
    }
  }
}

// ------- fused: gather(CSR) + residual + MLP + LN + attention scores -------
// One launch per relation r: keeps that relation's nf slice (51.2 MB of
// 128B lines) L3-resident across its ~16x gather re-reads.
__global__ __launch_bounds__(BLK)
void k_mlp(const float* __restrict__ nf, const float* __restrict__ W1, const float* __restrict__ b1,
           const float* __restrict__ W2, const float* __restrict__ b2,
           const float* __restrict__ Ws1, const float* __restrict__ Ws2,
           const float* __restrict__ gamma, const float* __restrict__ beta,
           const int* __restrict__ off, const int* __restrict__ sortedSrc,
           float* __restrict__ S, float* __restrict__ out, int r) {
  __shared__ float sA[TN][DD];                 // 16 KB
  __shared__ __align__(16) float sW[64 * DD];  // 32 KB  (total 48 KB)

  const int tid = threadIdx.x;
  const int n0 = blockIdx.x * TN;
  const int j = tid & 127;
  const int g = tid >> 7;  // 0..1

  // ---- stage rst = feat + gather(CSR) -> sA; each wave owns 8 rows ----
  {
    const int wv = tid >> 6;
    const int lane = tid & 63;
    const int* ss = sortedSrc + (size_t)r * EE;
#pragma unroll
    for (int q = 0; q < 8; ++q) {
      const int i = wv * 8 + q;
      const int n = n0 + i;
      float2 acc2 = make_float2(0.f, 0.f);
      if (n < NN) {
        acc2 = *(const float2*)(nf + ((size_t)n * RR + r) * DD + lane * 2);
        const int e1 = off[(size_t)r * (NN + 1) + n + 1];
        int e = off[(size_t)r * (NN + 1) + n];
        for (; e + 3 < e1; e += 4) {  // unroll-4: 4 row-loads in flight
          const int s0 = ss[e], s1 = ss[e + 1], s2 = ss[e + 2], s3 = ss[e + 3];
          const float2 v0 = *(const float2*)(nf + ((size_t)s0 * RR + r) * DD + lane * 2);
          const float2 v1 = *(const float2*)(nf + ((size_t)s1 * RR + r) * DD + lane * 2);
          const float2 v2 = *(const float2*)(nf + ((size_t)s2 * RR + r) * DD + lane * 2);
          const float2 v3 = *(const float2*)(nf + ((size_t)s3 * RR + r) * DD + lane * 2);
          acc2.x += (v0.x + v1.x) + (v2.x + v3.x);
          acc2.y += (v0.y + v1.y) + (v2.y + v3.y);
        }
        for (; e < e1; ++e) {
          const int s0 = ss[e];
          const float2 v0 = *(const float2*)(nf + ((size_t)s0 * RR + r) * DD + lane * 2);
          acc2.x += v0.x;
          acc2.y += v0.y;
        }
      }
      *(float2*)(&sA[i][lane * 2]) = acc2;
    }
  }
  loadWh(W1, 0, sW, tid);
  __syncthreads();

  float acc[16];
#pragma unroll
  for (int ii = 0; ii < 16; ++ii) acc[ii] = 0.f;

  // ---- GEMM1 ----
  gemm_half(sA, sW, j, g, 0, acc);
  __syncthreads();
  loadWh(W1, 1, sW, tid);
  __syncthreads();
  gemm_half(sA, sW, j, g, 64, acc);
  __syncthreads();
  {
    const float bb = b1[j];
#pragma unroll
    for (int ii = 0; ii < 16; ++ii) sA[g + ii * 2][j] = fmaxf(acc[ii] + bb, 0.f);
  }
  loadWh(W2, 0, sW, tid);
  __syncthreads();

  // ---- GEMM2 ----
#pragma unroll
  for (int ii = 0; ii < 16; ++ii) acc[ii] = 0.f;
  gemm_half(sA, sW, j, g, 0, acc);
  __syncthreads();
  loadWh(W2, 1, sW, tid);
  __syncthreads();
  gemm_half(sA, sW, j, g, 64, acc);
  __syncthreads();
  {
    const float bb = b2[j];
#pragma unroll
    for (int ii = 0; ii < 16; ++ii) sA[g + ii * 2][j] = fmaxf(acc[ii] + bb, 0.f);
  }
  loadWh(Ws1 + (size_t)r * DD * DD, 0, sW, tid);
  __syncthreads();

  // ---- LayerNorm (8 threads/row, stats in registers via shfl) ----
  {
    const int i = tid >> 3;          // 0..31
    const int c0 = (tid & 7) * 16;
    float s = 0.f, s2 = 0.f;
    float hv[16];
#pragma unroll
    for (int c = 0; c < 16; ++c) {
      const float v = sA[i][c0 + c];
      hv[c] = v;
      s += v; s2 += v * v;
    }
#pragma unroll
    for (int off2 = 1; off2 < 8; off2 <<= 1) {
      s  += __shfl_xor(s, off2);
      s2 += __shfl_xor(s2, off2);
    }
    const float mu = s * (1.f / 128.f);
    const float var = fmaxf(s2 * (1.f / 128.f) - mu * mu, 0.f);
    const float rs = rsqrtf(var + 1e-5f);
    const int n = n0 + i;
#pragma unroll
    for (int c = 0; c < 16; ++c) {
      hv[c] = (hv[c] - mu) * rs * gamma[c0 + c] + beta[c0 + c];
      sA[i][c0 + c] = hv[c];   // own slice only: no cross-thread hazard
    }
    if (n < NN) {
      float4* op = (float4*)(out + ((size_t)n * RR + r) * DD + c0);
#pragma unroll
      for (int q = 0; q < 4; ++q)
        op[q] = make_float4(hv[q * 4], hv[q * 4 + 1], hv[q * 4 + 2], hv[q * 4 + 3]);
    }
  }
  __syncthreads();

  // ---- GEMM3: tanh(h @ Ws1[r]) ----
#pragma unroll
  for (int ii = 0; ii < 16; ++ii) acc[ii] = 0.f;
  gemm_half(sA, sW, j, g, 0, acc);
  __syncthreads();
  loadWh(Ws1 + (size_t)r * DD * DD, 1, sW, tid);
  __syncthreads();
  gemm_half(sA, sW, j, g, 64, acc);
  __syncthreads();
#pragma unroll
  for (int ii = 0; ii < 16; ++ii) sA[g + ii * 2][j] = tanhf(acc[ii]);
  {
    sW[tid]       = Ws2[(size_t)r * 512 + tid];
    sW[tid + 256] = Ws2[(size_t)r * 512 + tid + 256];
  }
  __syncthreads();

  // ---- scores = tanh(...) @ Ws2[r] -> S ----
  if (tid < TN * 4) {
    const int i = tid >> 2;
    const int k = tid & 3;
    float a = 0.f;
#pragma unroll 8
    for (int q = 0; q < DD; ++q) a = fmaf(sA[i][q], sW[q * 4 + k], a);
    const int n = n0 + i;
    if (n < NN) S[((size_t)r * NN + n) * 4 + k] = a;
  }
}

// -------- softmax over relations + final mix (in place on out) --------
__global__ __launch_bounds__(256)
void k_combine(const float* __restrict__ S, float* __restrict__ out) {
  const long gw = (((long)blockIdx.x * 256) + threadIdx.x) >> 6;
  const int lane = threadIdx.x & 63;
  if (gw >= NN) return;
  const int n = (int)gw;
  float a[4][4];
#pragma unroll
  for (int r = 0; r < 4; ++r)
#pragma unroll
    for (int k = 0; k < 4; ++k)
      a[r][k] = S[((size_t)r * NN + n) * 4 + k];
#pragma unroll
  for (int k = 0; k < 4; ++k) {
    const float m = fmaxf(fmaxf(a[0][k], a[1][k]), fmaxf(a[2][k], a[3][k]));
    const float e0 = expf(a[0][k] - m);
    const float e1 = expf(a[1][k] - m);
    const float e2 = expf(a[2][k] - m);
    const float e3 = expf(a[3][k] - m);
    const float inv = 1.f / (e0 + e1 + e2 + e3);
    a[0][k] = e0 * inv; a[1][k] = e1 * inv; a[2][k] = e2 * inv; a[3][k] = e3 * inv;
  }
  float2 hv[4];
#pragma unroll
  for (int k = 0; k < 4; ++k)
    hv[k] = *(const float2*)(out + ((size_t)n * RR + k) * DD + lane * 2);
#pragma unroll
  for (int r = 0; r < 4; ++r) {
    float2 o;
    o.x = a[r][0] * hv[0].x + a[r][1] * hv[1].x + a[r][2] * hv[2].x + a[r][3] * hv[3].x;
    o.y = a[r][0] * hv[0].y + a[r][1] * hv[1].y + a[r][2] * hv[2].y + a[r][3] * hv[3].y;
    *(float2*)(out + ((size_t)n * RR + r) * DD + lane * 2) = o;
  }
}

extern "C" void kernel_launch(void* const* d_in, const int* in_sizes, int n_in,
                              void* d_out, int out_size, void* d_ws, size_t ws_size,
                              hipStream_t stream) {
  const float* nf    = (const float*)d_in[0];
  const int*   src   = (const int*)d_in[1];
  const int*   dst   = (const int*)d_in[2];
  const float* W1    = (const float*)d_in[3];
  const float* b1    = (const float*)d_in[4];
  const float* W2    = (const float*)d_in[5];
  const float* b2    = (const float*)d_in[6];
  const float* Ws1   = (const float*)d_in[7];
  const float* Ws2   = (const float*)d_in[8];
  const float* gamma = (const float*)d_in[9];
  const float* beta  = (const float*)d_in[10];
  float* out = (float*)d_out;

  // ws layout (~35.3 MB):
  //   S      : RR*NN*4 f32   (6.4 MB)
  //   off    : RR*(NN+1) int (1.6 MB)   CSR offsets
  //   cursor : RR*NN int     (1.6 MB)   fill cursors
  //   bsum   : RR*NB int     (1.6 KB)   scan block sums
  //   sorted : RR*EE int     (25.6 MB)  src indices grouped by dst
  float* S      = (float*)d_ws;
  int*   off    = (int*)(S + (size_t)RR * NN * 4);
  int*   cursor = off + (size_t)RR * (NN + 1);
  int*   bsum   = cursor + (size_t)RR * NN;
  int*   sorted = bsum + (size_t)RR * NB;

  hipMemsetAsync(off, 0, (size_t)RR * (NN + 1) * sizeof(int), stream);
  {
    dim3 grid((EE + 255) / 256, RR);
    k_hist<<<grid, dim3(256), 0, stream>>>(dst, off);
  }
  k_scan1<<<dim3(NB, RR), dim3(1024), 0, stream>>>(off, bsum);
  k_scan2<<<dim3(RR), dim3(128), 0, stream>>>(bsum);
  k_scan3<<<dim3(NB, RR), dim3(1024), 0, stream>>>(off, bsum, cursor);
  {
    dim3 grid((EE + 255) / 256, RR);
    k_fill<<<grid, dim3(256), 0, stream>>>(src, dst, cursor, sorted);
  }
  for (int r = 0; r < RR; ++r) {
    dim3 grid((NN + TN - 1) / TN);
    k_mlp<<<grid, dim3(BLK), 0, stream>>>(nf, W1, b1, W2, b2, Ws1, Ws2,
                                          gamma, beta, off, sorted, S, out, r);
  }
  {
    const long blocks = ((long)NN + 3) / 4;  // 1 wave/node
    k_combine<<<dim3((unsigned)blocks), dim3(256), 0, stream>>>(S, out);
  }
}

// Round 8
// 2048.145 us; speedup vs baseline: 3.1219x; 1.2458x over previous
//
#include <hip/hip_runtime.h>
#include <stdint.h>

#define NN 100000
#define RR 4
#define EE 1600000
#define DD 128
#define TN 32
#define BLK 256
#define NB 98  // ceil((NN+1)/1024)

// ---------- pass 1: histogram of dst (offsets shifted by +1) ----------
__global__ __launch_bounds__(256)
void k_hist(const int* __restrict__ dst, int* __restrict__ off) {
  const int r = blockIdx.y;
  const long e = (long)blockIdx.x * 256 + threadIdx.x;
  if (e >= EE) return;
  const int d = dst[(size_t)r * EE + e];
  atomicAdd(&off[(size_t)r * (NN + 1) + d + 1], 1);
}

// ---------- pass 2a: block-local inclusive scan ----------
__global__ __launch_bounds__(1024)
void k_scan1(int* __restrict__ off, int* __restrict__ bsum) {
  const int r = blockIdx.y;
  int* a = off + (size_t)r * (NN + 1);
  __shared__ int tmp[1024];
  const int t = threadIdx.x;
  const int idx = blockIdx.x * 1024 + t;
  tmp[t] = (idx <= NN) ? a[idx] : 0;
  __syncthreads();
  for (int o = 1; o < 1024; o <<= 1) {
    const int y = (t >= o) ? tmp[t - o] : 0;
    __syncthreads();
    tmp[t] += y;
    __syncthreads();
  }
  if (idx <= NN) a[idx] = tmp[t];
  if (t == 1023) bsum[r * NB + blockIdx.x] = tmp[1023];
}

// ---------- pass 2b: scan the 98 block sums -> exclusive prefix ----------
__global__ __launch_bounds__(128)
void k_scan2(int* __restrict__ bsum) {
  const int r = blockIdx.x;
  __shared__ int tmp[128];
  const int t = threadIdx.x;
  const int v = (t < NB) ? bsum[r * NB + t] : 0;
  tmp[t] = v;
  __syncthreads();
  for (int o = 1; o < 128; o <<= 1) {
    const int y = (t >= o) ? tmp[t - o] : 0;
    __syncthreads();
    tmp[t] += y;
    __syncthreads();
  }
  if (t < NB) bsum[r * NB + t] = tmp[t] - v;  // exclusive
}

// ---------- pass 2c: add block prefix; emit cursor copy ----------
__global__ __launch_bounds__(1024)
void k_scan3(int* __restrict__ off, const int* __restrict__ bsum,
             int* __restrict__ cursor) {
  const int r = blockIdx.y;
  const int idx = blockIdx.x * 1024 + threadIdx.x;
  const int add = bsum[r * NB + blockIdx.x];
  int* a = off + (size_t)r * (NN + 1);
  if (idx <= NN) {
    const int v = a[idx] + add;
    a[idx] = v;
    if (idx < NN) cursor[(size_t)r * NN + idx] = v;
  }
}

// ---------- pass 3: counting-sort fill of sortedSrc ----------
__global__ __launch_bounds__(256)
void k_fill(const int* __restrict__ src, const int* __restrict__ dst,
            int* __restrict__ cursor, int* __restrict__ sortedSrc) {
  const int r = blockIdx.y;
  const long e = (long)blockIdx.x * 256 + threadIdx.x;
  if (e >= EE) return;
  const int d = dst[(size_t)r * EE + e];
  const int pos = atomicAdd(&cursor[(size_t)r * NN + d], 1);
  sortedSrc[(size_t)r * EE + pos] = src[(size_t)r * EE + e];
}

// ---- copy one 64-row half of a 128x128 f32 weight into LDS ----
__device__ __forceinline__ void loadWh(const float* __restrict__ Wsrc, int half,
                                       float* __restrict__ sW, int tid) {
  const float4* src = (const float4*)(Wsrc + (size_t)half * 64 * DD);
  float4* dstv = (float4*)sW;
#pragma unroll
  for (int k = 0; k < 8; ++k) dstv[tid + k * BLK] = src[tid + k * BLK];  // 2048 float4
}

// ---- 4x4-blocked half-K gemm: acc[i][j] += A[rg+i][kbase+k] * W[k][c4+j] ----
// Per k-quad: 8 ds_read_b128 (~96 cyc) feed 64 FMAs (128 cyc) -> FMA-bound.
// A-reads are wave-broadcast (lanes 0-31 share rg); W-reads 16B-stride, 2-way.
__device__ __forceinline__ void gemm4x4(const float (*__restrict__ in)[DD],
                                        const float* __restrict__ sW,
                                        int rg, int c4, int kbase, float acc[4][4]) {
  for (int k4 = 0; k4 < 64; k4 += 4) {
    const float4 a0 = *(const float4*)(&in[rg + 0][kbase + k4]);
    const float4 a1 = *(const float4*)(&in[rg + 1][kbase + k4]);
    const float4 a2 = *(const float4*)(&in[rg + 2][kbase + k4]);
    const float4 a3 = *(const float4*)(&in[rg + 3][kbase + k4]);
    const float4 w0 = *(const float4*)(&sW[(k4 + 0) * DD + c4]);
    const float4 w1 = *(const float4*)(&sW[(k4 + 1) * DD + c4]);
    const float4 w2 = *(const float4*)(&sW[(k4 + 2) * DD + c4]);
    const float4 w3 = *(const float4*)(&sW[(k4 + 3) * DD + c4]);
#define ROWF(i, ai)                                                                               \
    acc[i][0] = fmaf(ai.x, w0.x, fmaf(ai.y, w1.x, fmaf(ai.z, w2.x, fmaf(ai.w, w3.x, acc[i][0])))); \
    acc[i][1] = fmaf(ai.x, w0.y, fmaf(ai.y, w1.y, fmaf(ai.z, w2.y, fmaf(ai.w, w3.y, acc[i][1])))); \
    acc[i][2] = fmaf(ai.x, w0.z, fmaf(ai.y, w1.z, fmaf(ai.z, w2.z, fmaf(ai.w, w3.z, acc[i][2])))); \
    acc[i][3] = fmaf(ai.x, w0.w, fmaf(ai.y, w1.w, fmaf(ai.z, w2.w, fmaf(ai.w, w3.w, acc[i][3]))));
    ROWF(0, a0) ROWF(1, a1) ROWF(2, a2) ROWF(3, a3)
#undef ROWF
  }
}

// ------- fused: gather(CSR) + residual + MLP + LN + attention scores -------
// One launch per relation r: keeps that relation's nf slice (51.2 MB of
// 128B lines) L3-resident across its ~16x gather re-reads.
__global__ __launch_bounds__(BLK)
void k_mlp(const float* __restrict__ nf, const float* __restrict__ W1, const float* __restrict__ b1,
           const float* __restrict__ W2, const float* __restrict__ b2,
           const float* __restrict__ Ws1, const float* __restrict__ Ws2,
           const float* __restrict__ gamma, const float* __restrict__ beta,
           const int* __restrict__ off, const int* __restrict__ sortedSrc,
           float* __restrict__ S, float* __restrict__ out, int r) {
  __shared__ float sA[TN][DD];                 // 16 KB
  __shared__ __align__(16) float sW[64 * DD];  // 32 KB  (total 48 KB)

  const int tid = threadIdx.x;
  const int n0 = blockIdx.x * TN;
  const int rg = (tid >> 5) * 4;   // 8 row groups of 4
  const int c4 = (tid & 31) * 4;   // 32 col groups of 4

  // ---- stage rst = feat + gather(CSR) -> sA; each wave owns 8 rows ----
  {
    const int wv = tid >> 6;
    const int lane = tid & 63;
    const int* ss = sortedSrc + (size_t)r * EE;
#pragma unroll
    for (int q = 0; q < 8; ++q) {
      const int i = wv * 8 + q;
      const int n = n0 + i;
      float2 acc2 = make_float2(0.f, 0.f);
      if (n < NN) {
        acc2 = *(const float2*)(nf + ((size_t)n * RR + r) * DD + lane * 2);
        const int e1 = off[(size_t)r * (NN + 1) + n + 1];
        int e = off[(size_t)r * (NN + 1) + n];
        for (; e + 3 < e1; e += 4) {  // unroll-4: 4 row-loads in flight
          const int s0 = ss[e], s1 = ss[e + 1], s2 = ss[e + 2], s3 = ss[e + 3];
          const float2 v0 = *(const float2*)(nf + ((size_t)s0 * RR + r) * DD + lane * 2);
          const float2 v1 = *(const float2*)(nf + ((size_t)s1 * RR + r) * DD + lane * 2);
          const float2 v2 = *(const float2*)(nf + ((size_t)s2 * RR + r) * DD + lane * 2);
          const float2 v3 = *(const float2*)(nf + ((size_t)s3 * RR + r) * DD + lane * 2);
          acc2.x += (v0.x + v1.x) + (v2.x + v3.x);
          acc2.y += (v0.y + v1.y) + (v2.y + v3.y);
        }
        for (; e < e1; ++e) {
          const int s0 = ss[e];
          const float2 v0 = *(const float2*)(nf + ((size_t)s0 * RR + r) * DD + lane * 2);
          acc2.x += v0.x;
          acc2.y += v0.y;
        }
      }
      *(float2*)(&sA[i][lane * 2]) = acc2;
    }
  }
  loadWh(W1, 0, sW, tid);
  __syncthreads();

  float acc[4][4];
#pragma unroll
  for (int i = 0; i < 4; ++i)
#pragma unroll
    for (int jj = 0; jj < 4; ++jj) acc[i][jj] = 0.f;

  // ---- GEMM1 ----
  gemm4x4(sA, sW, rg, c4, 0, acc);
  __syncthreads();
  loadWh(W1, 1, sW, tid);
  __syncthreads();
  gemm4x4(sA, sW, rg, c4, 64, acc);
  __syncthreads();
  {
    const float4 bb = *(const float4*)(&b1[c4]);
#pragma unroll
    for (int i = 0; i < 4; ++i)
      *(float4*)(&sA[rg + i][c4]) = make_float4(
          fmaxf(acc[i][0] + bb.x, 0.f), fmaxf(acc[i][1] + bb.y, 0.f),
          fmaxf(acc[i][2] + bb.z, 0.f), fmaxf(acc[i][3] + bb.w, 0.f));
  }
  loadWh(W2, 0, sW, tid);
  __syncthreads();

  // ---- GEMM2 ----
#pragma unroll
  for (int i = 0; i < 4; ++i)
#pragma unroll
    for (int jj = 0; jj < 4; ++jj) acc[i][jj] = 0.f;
  gemm4x4(sA, sW, rg, c4, 0, acc);
  __syncthreads();
  loadWh(W2, 1, sW, tid);
  __syncthreads();
  gemm4x4(sA, sW, rg, c4, 64, acc);
  __syncthreads();
  {
    const float4 bb = *(const float4*)(&b2[c4]);
#pragma unroll
    for (int i = 0; i < 4; ++i)
      *(float4*)(&sA[rg + i][c4]) = make_float4(
          fmaxf(acc[i][0] + bb.x, 0.f), fmaxf(acc[i][1] + bb.y, 0.f),
          fmaxf(acc[i][2] + bb.z, 0.f), fmaxf(acc[i][3] + bb.w, 0.f));
  }
  loadWh(Ws1 + (size_t)r * DD * DD, 0, sW, tid);
  __syncthreads();

  // ---- LayerNorm (8 threads/row, stats in registers via shfl) ----
  {
    const int i = tid >> 3;          // 0..31
    const int c0 = (tid & 7) * 16;
    float s = 0.f, s2 = 0.f;
    float hv[16];
#pragma unroll
    for (int c = 0; c < 16; ++c) {
      const float v = sA[i][c0 + c];
      hv[c] = v;
      s += v; s2 += v * v;
    }
#pragma unroll
    for (int off2 = 1; off2 < 8; off2 <<= 1) {
      s  += __shfl_xor(s, off2);
      s2 += __shfl_xor(s2, off2);
    }
    const float mu = s * (1.f / 128.f);
    const float var = fmaxf(s2 * (1.f / 128.f) - mu * mu, 0.f);
    const float rs = rsqrtf(var + 1e-5f);
    const int n = n0 + i;
#pragma unroll
    for (int c = 0; c < 16; ++c) {
      hv[c] = (hv[c] - mu) * rs * gamma[c0 + c] + beta[c0 + c];
      sA[i][c0 + c] = hv[c];   // own slice only: no cross-thread hazard
    }
    if (n < NN) {
      float4* op = (float4*)(out + ((size_t)n * RR + r) * DD + c0);
#pragma unroll
      for (int q = 0; q < 4; ++q)
        op[q] = make_float4(hv[q * 4], hv[q * 4 + 1], hv[q * 4 + 2], hv[q * 4 + 3]);
    }
  }
  __syncthreads();

  // ---- GEMM3: tanh(h @ Ws1[r]) ----
#pragma unroll
  for (int i = 0; i < 4; ++i)
#pragma unroll
    for (int jj = 0; jj < 4; ++jj) acc[i][jj] = 0.f;
  gemm4x4(sA, sW, rg, c4, 0, acc);
  __syncthreads();
  loadWh(Ws1 + (size_t)r * DD * DD, 1, sW, tid);
  __syncthreads();
  gemm4x4(sA, sW, rg, c4, 64, acc);
  __syncthreads();
#pragma unroll
  for (int i = 0; i < 4; ++i)
    *(float4*)(&sA[rg + i][c4]) = make_float4(
        tanhf(acc[i][0]), tanhf(acc[i][1]), tanhf(acc[i][2]), tanhf(acc[i][3]));
  {
    sW[tid]       = Ws2[(size_t)r * 512 + tid];
    sW[tid + 256] = Ws2[(size_t)r * 512 + tid + 256];
  }
  __syncthreads();

  // ---- scores = tanh(...) @ Ws2[r] -> S ----
  if (tid < TN * 4) {
    const int i = tid >> 2;
    const int k = tid & 3;
    float a = 0.f;
#pragma unroll 8
    for (int q = 0; q < DD; ++q) a = fmaf(sA[i][q], sW[q * 4 + k], a);
    const int n = n0 + i;
    if (n < NN) S[((size_t)r * NN + n) * 4 + k] = a;
  }
}

// -------- softmax over relations + final mix (in place on out) --------
__global__ __launch_bounds__(256)
void k_combine(const float* __restrict__ S, float* __restrict__ out) {
  const long gw = (((long)blockIdx.x * 256) + threadIdx.x) >> 6;
  const int lane = threadIdx.x & 63;
  if (gw >= NN) return;
  const int n = (int)gw;
  float a[4][4];
#pragma unroll
  for (int r = 0; r < 4; ++r)
#pragma unroll
    for (int k = 0; k < 4; ++k)
      a[r][k] = S[((size_t)r * NN + n) * 4 + k];
#pragma unroll
  for (int k = 0; k < 4; ++k) {
    const float m = fmaxf(fmaxf(a[0][k], a[1][k]), fmaxf(a[2][k], a[3][k]));
    const float e0 = expf(a[0][k] - m);
    const float e1 = expf(a[1][k] - m);
    const float e2 = expf(a[2][k] - m);
    const float e3 = expf(a[3][k] - m);
    const float inv = 1.f / (e0 + e1 + e2 + e3);
    a[0][k] = e0 * inv; a[1][k] = e1 * inv; a[2][k] = e2 * inv; a[3][k] = e3 * inv;
  }
  float2 hv[4];
#pragma unroll
  for (int k = 0; k < 4; ++k)
    hv[k] = *(const float2*)(out + ((size_t)n * RR + k) * DD + lane * 2);
#pragma unroll
  for (int r = 0; r < 4; ++r) {
    float2 o;
    o.x = a[r][0] * hv[0].x + a[r][1] * hv[1].x + a[r][2] * hv[2].x + a[r][3] * hv[3].x;
    o.y = a[r][0] * hv[0].y + a[r][1] * hv[1].y + a[r][2] * hv[2].y + a[r][3] * hv[3].y;
    *(float2*)(out + ((size_t)n * RR + r) * DD + lane * 2) = o;
  }
}

extern "C" void kernel_launch(void* const* d_in, const int* in_sizes, int n_in,
                              void* d_out, int out_size, void* d_ws, size_t ws_size,
                              hipStream_t stream) {
  const float* nf    = (const float*)d_in[0];
  const int*   src   = (const int*)d_in[1];
  const int*   dst   = (const int*)d_in[2];
  const float* W1    = (const float*)d_in[3];
  const float* b1    = (const float*)d_in[4];
  const float* W2    = (const float*)d_in[5];
  const float* b2    = (const float*)d_in[6];
  const float* Ws1   = (const float*)d_in[7];
  const float* Ws2   = (const float*)d_in[8];
  const float* gamma = (const float*)d_in[9];
  const float* beta  = (const float*)d_in[10];
  float* out = (float*)d_out;

  // ws layout (~35.3 MB):
  float* S      = (float*)d_ws;
  int*   off    = (int*)(S + (size_t)RR * NN * 4);
  int*   cursor = off + (size_t)RR * (NN + 1);
  int*   bsum   = cursor + (size_t)RR * NN;
  int*   sorted = bsum + (size_t)RR * NB;

  hipMemsetAsync(off, 0, (size_t)RR * (NN + 1) * sizeof(int), stream);
  {
    dim3 grid((EE + 255) / 256, RR);
    k_hist<<<grid, dim3(256), 0, stream>>>(dst, off);
  }
  k_scan1<<<dim3(NB, RR), dim3(1024), 0, stream>>>(off, bsum);
  k_scan2<<<dim3(RR), dim3(128), 0, stream>>>(bsum);
  k_scan3<<<dim3(NB, RR), dim3(1024), 0, stream>>>(off, bsum, cursor);
  {
    dim3 grid((EE + 255) / 256, RR);
    k_fill<<<grid, dim3(256), 0, stream>>>(src, dst, cursor, sorted);
  }
  for (int r = 0; r < RR; ++r) {
    dim3 grid((NN + TN - 1) / TN);
    k_mlp<<<grid, dim3(BLK), 0, stream>>>(nf, W1, b1, W2, b2, Ws1, Ws2,
                                          gamma, beta, off, sorted, S, out, r);
  }
  {
    const long blocks = ((long)NN + 3) / 4;  // 1 wave/node
    k_combine<<<dim3((unsigned)blocks), dim3(256), 0, stream>>>(S, out);
  }
}

// Round 9
// 1768.632 us; speedup vs baseline: 3.6153x; 1.1580x over previous
//
#include <hip/hip_runtime.h>
#include <stdint.h>

#define NN 100000
#define RR 4
#define EE 1600000
#define DD 128
#define TN 32
#define BLK 256
#define NB 98     // ceil((NN+1)/1024) scan blocks; ALSO # of 1024-node buckets
#define CHUNK 2048

// ---------- pass 1: histogram of dst (offsets shifted by +1) ----------
__global__ __launch_bounds__(256)
void k_hist(const int* __restrict__ dst, int* __restrict__ off) {
  const int r = blockIdx.y;
  const long e = (long)blockIdx.x * 256 + threadIdx.x;
  if (e >= EE) return;
  const int d = dst[(size_t)r * EE + e];
  atomicAdd(&off[(size_t)r * (NN + 1) + d + 1], 1);
}

// ---------- pass 2a: block-local inclusive scan ----------
__global__ __launch_bounds__(1024)
void k_scan1(int* __restrict__ off, int* __restrict__ bsum) {
  const int r = blockIdx.y;
  int* a = off + (size_t)r * (NN + 1);
  __shared__ int tmp[1024];
  const int t = threadIdx.x;
  const int idx = blockIdx.x * 1024 + t;
  tmp[t] = (idx <= NN) ? a[idx] : 0;
  __syncthreads();
  for (int o = 1; o < 1024; o <<= 1) {
    const int y = (t >= o) ? tmp[t - o] : 0;
    __syncthreads();
    tmp[t] += y;
    __syncthreads();
  }
  if (idx <= NN) a[idx] = tmp[t];
  if (t == 1023) bsum[r * NB + blockIdx.x] = tmp[1023];
}

// ---------- pass 2b: scan the 98 block sums -> exclusive prefix ----------
__global__ __launch_bounds__(128)
void k_scan2(int* __restrict__ bsum) {
  const int r = blockIdx.x;
  __shared__ int tmp[128];
  const int t = threadIdx.x;
  const int v = (t < NB) ? bsum[r * NB + t] : 0;
  tmp[t] = v;
  __syncthreads();
  for (int o = 1; o < 128; o <<= 1) {
    const int y = (t >= o) ? tmp[t - o] : 0;
    __syncthreads();
    tmp[t] += y;
    __syncthreads();
  }
  if (t < NB) bsum[r * NB + t] = tmp[t] - v;  // exclusive
}

// ---------- pass 2c: add block prefix; emit cursor copy ----------
__global__ __launch_bounds__(1024)
void k_scan3(int* __restrict__ off, const int* __restrict__ bsum,
             int* __restrict__ cursor) {
  const int r = blockIdx.y;
  const int idx = blockIdx.x * 1024 + threadIdx.x;
  const int add = bsum[r * NB + blockIdx.x];
  int* a = off + (size_t)r * (NN + 1);
  if (idx <= NN) {
    const int v = a[idx] + add;
    a[idx] = v;
    if (idx < NN) cursor[(size_t)r * NN + idx] = v;
  }
}

// ---------- init coarse-bucket cursors from CSR offsets ----------
__global__ __launch_bounds__(256)
void k_initg(const int* __restrict__ off, int* __restrict__ gcur) {
  const int i = blockIdx.x * 256 + threadIdx.x;
  if (i < RR * NB) {
    const int r = i / NB, b = i % NB;
    gcur[i] = off[(size_t)r * (NN + 1) + (b << 10)];
  }
}

// ---------- pass 3a: coarse binning with LDS-staged dense writes ----------
__global__ __launch_bounds__(256)
void k_bin(const int* __restrict__ src, const int* __restrict__ dst,
           int* __restrict__ gcur, int2* __restrict__ pairs) {
  const int r = blockIdx.y;
  const long base = (long)blockIdx.x * CHUNK;
  const int t = threadIdx.x;
  __shared__ int hist[NB], lofs[NB], gbase[NB], hcur[NB];
  __shared__ int2 stage[CHUNK];  // 16 KB
  for (int i = t; i < NB; i += 256) hist[i] = 0;
  __syncthreads();
  int d[8], s[8];
#pragma unroll
  for (int k = 0; k < 8; ++k) {
    const long e = base + k * 256 + t;
    if (e < EE) {
      d[k] = dst[(size_t)r * EE + e];
      s[k] = src[(size_t)r * EE + e];
      atomicAdd(&hist[d[k] >> 10], 1);
    } else d[k] = -1;
  }
  __syncthreads();
  if (t == 0) {
    int run = 0;
    for (int b = 0; b < NB; ++b) { lofs[b] = run; run += hist[b]; }
  }
  __syncthreads();
  if (t < NB) {
    hcur[t] = 0;
    gbase[t] = hist[t] ? atomicAdd(&gcur[r * NB + t], hist[t]) : 0;
  }
  __syncthreads();
#pragma unroll
  for (int k = 0; k < 8; ++k) {
    if (d[k] >= 0) {
      const int b = d[k] >> 10;
      const int slot = lofs[b] + atomicAdd(&hcur[b], 1);
      stage[slot] = make_int2(d[k], s[k]);
    }
  }
  __syncthreads();
  const int total = (int)((EE - base < CHUNK) ? (EE - base) : CHUNK);
  for (int i = t; i < total; i += 256) {
    const int2 p = stage[i];
    const int b = p.x >> 10;
    pairs[(size_t)r * EE + gbase[b] + (i - lofs[b])] = p;
  }
}

// ---------- pass 3b: exact placement within L2-resident bucket window ----------
__global__ __launch_bounds__(256)
void k_place(const int2* __restrict__ pairs, const int* __restrict__ off,
             int* __restrict__ cursor, int* __restrict__ sorted) {
  const int r = blockIdx.y;
  const int b = blockIdx.x;
  const int nlo = b << 10;
  const int nhi = (nlo + 1024 < NN) ? nlo + 1024 : NN;
  const int span0 = off[(size_t)r * (NN + 1) + nlo];
  const int span1 = off[(size_t)r * (NN + 1) + nhi];
  for (int i = span0 + threadIdx.x; i < span1; i += 256) {
    const int2 p = pairs[(size_t)r * EE + i];
    const int pos = atomicAdd(&cursor[(size_t)r * NN + p.x], 1);
    sorted[(size_t)r * EE + pos] = p.y;
  }
}

// ---- copy one 64-row half of a 128x128 f32 weight into LDS ----
__device__ __forceinline__ void loadWh(const float* __restrict__ Wsrc, int half,
                                       float* __restrict__ sW, int tid) {
  const float4* src = (const float4*)(Wsrc + (size_t)half * 64 * DD);
  float4* dstv = (float4*)sW;
#pragma unroll
  for (int k = 0; k < 8; ++k) dstv[tid + k * BLK] = src[tid + k * BLK];  // 2048 float4
}

// ---- 4x4-blocked half-K gemm ----
__device__ __forceinline__ void gemm4x4(const float (*__restrict__ in)[DD],
                                        const float* __restrict__ sW,
                                        int rg, int c4, int kbase, float acc[4][4]) {
  for (int k4 = 0; k4 < 64; k4 += 4) {
    const float4 a0 = *(const float4*)(&in[rg + 0][kbase + k4]);
    const float4 a1 = *(const float4*)(&in[rg + 1][kbase + k4]);
    const float4 a2 = *(const float4*)(&in[rg + 2][kbase + k4]);
    const float4 a3 = *(const float4*)(&in[rg + 3][kbase + k4]);
    const float4 w0 = *(const float4*)(&sW[(k4 + 0) * DD + c4]);
    const float4 w1 = *(const float4*)(&sW[(k4 + 1) * DD + c4]);
    const float4 w2 = *(const float4*)(&sW[(k4 + 2) * DD + c4]);
    const float4 w3 = *(const float4*)(&sW[(k4 + 3) * DD + c4]);
#define ROWF(i, ai)                                                                               \
    acc[i][0] = fmaf(ai.x, w0.x, fmaf(ai.y, w1.x, fmaf(ai.z, w2.x, fmaf(ai.w, w3.x, acc[i][0])))); \
    acc[i][1] = fmaf(ai.x, w0.y, fmaf(ai.y, w1.y, fmaf(ai.z, w2.y, fmaf(ai.w, w3.y, acc[i][1])))); \
    acc[i][2] = fmaf(ai.x, w0.z, fmaf(ai.y, w1.z, fmaf(ai.z, w2.z, fmaf(ai.w, w3.z, acc[i][2])))); \
    acc[i][3] = fmaf(ai.x, w0.w, fmaf(ai.y, w1.w, fmaf(ai.z, w2.w, fmaf(ai.w, w3.w, acc[i][3]))));
    ROWF(0, a0) ROWF(1, a1) ROWF(2, a2) ROWF(3, a3)
#undef ROWF
  }
}

// ------- fused: gather(CSR) + residual + MLP + LN + attention scores -------
__global__ __launch_bounds__(BLK)
void k_mlp(const float* __restrict__ nf, const float* __restrict__ W1, const float* __restrict__ b1,
           const float* __restrict__ W2, const float* __restrict__ b2,
           const float* __restrict__ Ws1, const float* __restrict__ Ws2,
           const float* __restrict__ gamma, const float* __restrict__ beta,
           const int* __restrict__ off, const int* __restrict__ sortedSrc,
           float* __restrict__ S, float* __restrict__ out, int r) {
  __shared__ float sA[TN][DD];                 // 16 KB
  __shared__ __align__(16) float sW[64 * DD];  // 32 KB  (total 48 KB)

  const int tid = threadIdx.x;
  const int n0 = blockIdx.x * TN;
  const int rg = (tid >> 5) * 4;   // 8 row groups of 4
  const int c4 = (tid & 31) * 4;   // 32 col groups of 4

  // ---- stage rst = feat + gather(CSR) -> sA; each wave owns 8 rows ----
  {
    const int wv = tid >> 6;
    const int lane = tid & 63;
    const int* ss = sortedSrc + (size_t)r * EE;
#pragma unroll
    for (int q = 0; q < 8; ++q) {
      const int i = wv * 8 + q;
      const int n = n0 + i;
      float2 acc2 = make_float2(0.f, 0.f);
      if (n < NN) {
        acc2 = *(const float2*)(nf + ((size_t)n * RR + r) * DD + lane * 2);
        const int e1 = off[(size_t)r * (NN + 1) + n + 1];
        int e = off[(size_t)r * (NN + 1) + n];
        for (; e + 3 < e1; e += 4) {  // unroll-4: 4 row-loads in flight
          const int s0 = ss[e], s1 = ss[e + 1], s2 = ss[e + 2], s3 = ss[e + 3];
          const float2 v0 = *(const float2*)(nf + ((size_t)s0 * RR + r) * DD + lane * 2);
          const float2 v1 = *(const float2*)(nf + ((size_t)s1 * RR + r) * DD + lane * 2);
          const float2 v2 = *(const float2*)(nf + ((size_t)s2 * RR + r) * DD + lane * 2);
          const float2 v3 = *(const float2*)(nf + ((size_t)s3 * RR + r) * DD + lane * 2);
          acc2.x += (v0.x + v1.x) + (v2.x + v3.x);
          acc2.y += (v0.y + v1.y) + (v2.y + v3.y);
        }
        for (; e < e1; ++e) {
          const int s0 = ss[e];
          const float2 v0 = *(const float2*)(nf + ((size_t)s0 * RR + r) * DD + lane * 2);
          acc2.x += v0.x;
          acc2.y += v0.y;
        }
      }
      *(float2*)(&sA[i][lane * 2]) = acc2;
    }
  }
  loadWh(W1, 0, sW, tid);
  __syncthreads();

  float acc[4][4];
#pragma unroll
  for (int i = 0; i < 4; ++i)
#pragma unroll
    for (int jj = 0; jj < 4; ++jj) acc[i][jj] = 0.f;

  // ---- GEMM1 ----
  gemm4x4(sA, sW, rg, c4, 0, acc);
  __syncthreads();
  loadWh(W1, 1, sW, tid);
  __syncthreads();
  gemm4x4(sA, sW, rg, c4, 64, acc);
  __syncthreads();
  {
    const float4 bb = *(const float4*)(&b1[c4]);
#pragma unroll
    for (int i = 0; i < 4; ++i)
      *(float4*)(&sA[rg + i][c4]) = make_float4(
          fmaxf(acc[i][0] + bb.x, 0.f), fmaxf(acc[i][1] + bb.y, 0.f),
          fmaxf(acc[i][2] + bb.z, 0.f), fmaxf(acc[i][3] + bb.w, 0.f));
  }
  loadWh(W2, 0, sW, tid);
  __syncthreads();

  // ---- GEMM2 ----
#pragma unroll
  for (int i = 0; i < 4; ++i)
#pragma unroll
    for (int jj = 0; jj < 4; ++jj) acc[i][jj] = 0.f;
  gemm4x4(sA, sW, rg, c4, 0, acc);
  __syncthreads();
  loadWh(W2, 1, sW, tid);
  __syncthreads();
  gemm4x4(sA, sW, rg, c4, 64, acc);
  __syncthreads();
  {
    const float4 bb = *(const float4*)(&b2[c4]);
#pragma unroll
    for (int i = 0; i < 4; ++i)
      *(float4*)(&sA[rg + i][c4]) = make_float4(
          fmaxf(acc[i][0] + bb.x, 0.f), fmaxf(acc[i][1] + bb.y, 0.f),
          fmaxf(acc[i][2] + bb.z, 0.f), fmaxf(acc[i][3] + bb.w, 0.f));
  }
  loadWh(Ws1 + (size_t)r * DD * DD, 0, sW, tid);
  __syncthreads();

  // ---- LayerNorm (8 threads/row, stats in registers via shfl) ----
  {
    const int i = tid >> 3;          // 0..31
    const int c0 = (tid & 7) * 16;
    float s = 0.f, s2 = 0.f;
    float hv[16];
#pragma unroll
    for (int c = 0; c < 16; ++c) {
      const float v = sA[i][c0 + c];
      hv[c] = v;
      s += v; s2 += v * v;
    }
#pragma unroll
    for (int off2 = 1; off2 < 8; off2 <<= 1) {
      s  += __shfl_xor(s, off2);
      s2 += __shfl_xor(s2, off2);
    }
    const float mu = s * (1.f / 128.f);
    const float var = fmaxf(s2 * (1.f / 128.f) - mu * mu, 0.f);
    const float rs = rsqrtf(var + 1e-5f);
    const int n = n0 + i;
#pragma unroll
    for (int c = 0; c < 16; ++c) {
      hv[c] = (hv[c] - mu) * rs * gamma[c0 + c] + beta[c0 + c];
      sA[i][c0 + c] = hv[c];   // own slice only: no cross-thread hazard
    }
    if (n < NN) {
      float4* op = (float4*)(out + ((size_t)n * RR + r) * DD + c0);
#pragma unroll
      for (int q = 0; q < 4; ++q)
        op[q] = make_float4(hv[q * 4], hv[q * 4 + 1], hv[q * 4 + 2], hv[q * 4 + 3]);
    }
  }
  __syncthreads();

  // ---- GEMM3: tanh(h @ Ws1[r]) ----
#pragma unroll
  for (int i = 0; i < 4; ++i)
#pragma unroll
    for (int jj = 0; jj < 4; ++jj) acc[i][jj] = 0.f;
  gemm4x4(sA, sW, rg, c4, 0, acc);
  __syncthreads();
  loadWh(Ws1 + (size_t)r * DD * DD, 1, sW, tid);
  __syncthreads();
  gemm4x4(sA, sW, rg, c4, 64, acc);
  __syncthreads();
#pragma unroll
  for (int i = 0; i < 4; ++i)
    *(float4*)(&sA[rg + i][c4]) = make_float4(
        tanhf(acc[i][0]), tanhf(acc[i][1]), tanhf(acc[i][2]), tanhf(acc[i][3]));
  {
    sW[tid]       = Ws2[(size_t)r * 512 + tid];
    sW[tid + 256] = Ws2[(size_t)r * 512 + tid + 256];
  }
  __syncthreads();

  // ---- scores = tanh(...) @ Ws2[r] -> S ----
  if (tid < TN * 4) {
    const int i = tid >> 2;
    const int k = tid & 3;
    float a = 0.f;
#pragma unroll 8
    for (int q = 0; q < DD; ++q) a = fmaf(sA[i][q], sW[q * 4 + k], a);
    const int n = n0 + i;
    if (n < NN) S[((size_t)r * NN + n) * 4 + k] = a;
  }
}

// -------- softmax over relations + final mix (in place on out) --------
__global__ __launch_bounds__(256)
void k_combine(const float* __restrict__ S, float* __restrict__ out) {
  const long gw = (((long)blockIdx.x * 256) + threadIdx.x) >> 6;
  const int lane = threadIdx.x & 63;
  if (gw >= NN) return;
  const int n = (int)gw;
  float a[4][4];
#pragma unroll
  for (int r = 0; r < 4; ++r)
#pragma unroll
    for (int k = 0; k < 4; ++k)
      a[r][k] = S[((size_t)r * NN + n) * 4 + k];
#pragma unroll
  for (int k = 0; k < 4; ++k) {
    const float m = fmaxf(fmaxf(a[0][k], a[1][k]), fmaxf(a[2][k], a[3][k]));
    const float e0 = expf(a[0][k] - m);
    const float e1 = expf(a[1][k] - m);
    const float e2 = expf(a[2][k] - m);
    const float e3 = expf(a[3][k] - m);
    const float inv = 1.f / (e0 + e1 + e2 + e3);
    a[0][k] = e0 * inv; a[1][k] = e1 * inv; a[2][k] = e2 * inv; a[3][k] = e3 * inv;
  }
  float2 hv[4];
#pragma unroll
  for (int k = 0; k < 4; ++k)
    hv[k] = *(const float2*)(out + ((size_t)n * RR + k) * DD + lane * 2);
#pragma unroll
  for (int r = 0; r < 4; ++r) {
    float2 o;
    o.x = a[r][0] * hv[0].x + a[r][1] * hv[1].x + a[r][2] * hv[2].x + a[r][3] * hv[3].x;
    o.y = a[r][0] * hv[0].y + a[r][1] * hv[1].y + a[r][2] * hv[2].y + a[r][3] * hv[3].y;
    *(float2*)(out + ((size_t)n * RR + r) * DD + lane * 2) = o;
  }
}

extern "C" void kernel_launch(void* const* d_in, const int* in_sizes, int n_in,
                              void* d_out, int out_size, void* d_ws, size_t ws_size,
                              hipStream_t stream) {
  const float* nf    = (const float*)d_in[0];
  const int*   src   = (const int*)d_in[1];
  const int*   dst   = (const int*)d_in[2];
  const float* W1    = (const float*)d_in[3];
  const float* b1    = (const float*)d_in[4];
  const float* W2    = (const float*)d_in[5];
  const float* b2    = (const float*)d_in[6];
  const float* Ws1   = (const float*)d_in[7];
  const float* Ws2   = (const float*)d_in[8];
  const float* gamma = (const float*)d_in[9];
  const float* beta  = (const float*)d_in[10];
  float* out = (float*)d_out;

  // ws layout (~88 MB; ws proven >= 211 MB in round 5):
  //   S      : RR*NN*4 f32   (6.4 MB)
  //   off    : RR*(NN+1) int (1.6 MB)   CSR offsets
  //   cursor : RR*NN int     (1.6 MB)   node fill cursors
  //   bsum   : RR*NB int                scan block sums
  //   gcur   : RR*NB int                coarse-bucket cursors
  //   pairs  : RR*EE int2    (51.2 MB)  coarse-binned (dst,src)
  //   sorted : RR*EE int     (25.6 MB)  src grouped by dst
  float* S      = (float*)d_ws;
  int*   off    = (int*)(S + (size_t)RR * NN * 4);
  int*   cursor = off + (size_t)RR * (NN + 1);
  int*   bsum   = cursor + (size_t)RR * NN;
  int*   gcur   = bsum + (size_t)RR * NB;
  int2*  pairs  = (int2*)(gcur + (size_t)RR * NB);
  int*   sorted = (int*)(pairs + (size_t)RR * EE);

  hipMemsetAsync(off, 0, (size_t)RR * (NN + 1) * sizeof(int), stream);
  {
    dim3 grid((EE + 255) / 256, RR);
    k_hist<<<grid, dim3(256), 0, stream>>>(dst, off);
  }
  k_scan1<<<dim3(NB, RR), dim3(1024), 0, stream>>>(off, bsum);
  k_scan2<<<dim3(RR), dim3(128), 0, stream>>>(bsum);
  k_scan3<<<dim3(NB, RR), dim3(1024), 0, stream>>>(off, bsum, cursor);
  k_initg<<<dim3((RR * NB + 255) / 256), dim3(256), 0, stream>>>(off, gcur);
  {
    dim3 grid((EE + CHUNK - 1) / CHUNK, RR);
    k_bin<<<grid, dim3(256), 0, stream>>>(src, dst, gcur, pairs);
  }
  k_place<<<dim3(NB, RR), dim3(256), 0, stream>>>(pairs, off, cursor, sorted);
  for (int r = 0; r < RR; ++r) {
    dim3 grid((NN + TN - 1) / TN);
    k_mlp<<<grid, dim3(BLK), 0, stream>>>(nf, W1, b1, W2, b2, Ws1, Ws2,
                                          gamma, beta, off, sorted, S, out, r);
  }
  {
    const long blocks = ((long)NN + 3) / 4;  // 1 wave/node
    k_combine<<<dim3((unsigned)blocks), dim3(256), 0, stream>>>(S, out);
  }
}

// Round 10
// 1728.871 us; speedup vs baseline: 3.6985x; 1.0230x over previous
//
#include <hip/hip_runtime.h>
#include <stdint.h>

#define NN 100000
#define RR 4
#define EE 1600000
#define DD 128
#define TN 32
#define BLK 256
#define NB 98     // ceil((NN+1)/1024) scan blocks; ALSO # of 1024-node buckets
#define CHUNK 2048

typedef unsigned int u32;
typedef unsigned short u16;

__device__ __forceinline__ u16 f2bf(float f) {
  union { float f; u32 i; } c; c.f = f;
  const u32 lsb = (c.i >> 16) & 1u;
  c.i += 0x7fffu + lsb;  // round-to-nearest-even
  return (u16)(c.i >> 16);
}
__device__ __forceinline__ u32 pack2(float a, float b) {
  return (u32)f2bf(a) | ((u32)f2bf(b) << 16);
}
__device__ __forceinline__ float u2f(u32 u) {
  union { u32 i; float f; } c; c.i = u; return c.f;
}

// ---------- pass 1: histogram of dst (offsets shifted by +1) ----------
__global__ __launch_bounds__(256)
void k_hist(const int* __restrict__ dst, int* __restrict__ off) {
  const int r = blockIdx.y;
  const long e = (long)blockIdx.x * 256 + threadIdx.x;
  if (e >= EE) return;
  const int d = dst[(size_t)r * EE + e];
  atomicAdd(&off[(size_t)r * (NN + 1) + d + 1], 1);
}

// ---------- pass 2a: block-local inclusive scan ----------
__global__ __launch_bounds__(1024)
void k_scan1(int* __restrict__ off, int* __restrict__ bsum) {
  const int r = blockIdx.y;
  int* a = off + (size_t)r * (NN + 1);
  __shared__ int tmp[1024];
  const int t = threadIdx.x;
  const int idx = blockIdx.x * 1024 + t;
  tmp[t] = (idx <= NN) ? a[idx] : 0;
  __syncthreads();
  for (int o = 1; o < 1024; o <<= 1) {
    const int y = (t >= o) ? tmp[t - o] : 0;
    __syncthreads();
    tmp[t] += y;
    __syncthreads();
  }
  if (idx <= NN) a[idx] = tmp[t];
  if (t == 1023) bsum[r * NB + blockIdx.x] = tmp[1023];
}

// ---------- pass 2b: scan the 98 block sums -> exclusive prefix ----------
__global__ __launch_bounds__(128)
void k_scan2(int* __restrict__ bsum) {
  const int r = blockIdx.x;
  __shared__ int tmp[128];
  const int t = threadIdx.x;
  const int v = (t < NB) ? bsum[r * NB + t] : 0;
  tmp[t] = v;
  __syncthreads();
  for (int o = 1; o < 128; o <<= 1) {
    const int y = (t >= o) ? tmp[t - o] : 0;
    __syncthreads();
    tmp[t] += y;
    __syncthreads();
  }
  if (t < NB) bsum[r * NB + t] = tmp[t] - v;  // exclusive
}

// ---------- pass 2c: add block prefix; emit cursor copy ----------
__global__ __launch_bounds__(1024)
void k_scan3(int* __restrict__ off, const int* __restrict__ bsum,
             int* __restrict__ cursor) {
  const int r = blockIdx.y;
  const int idx = blockIdx.x * 1024 + threadIdx.x;
  const int add = bsum[r * NB + blockIdx.x];
  int* a = off + (size_t)r * (NN + 1);
  if (idx <= NN) {
    const int v = a[idx] + add;
    a[idx] = v;
    if (idx < NN) cursor[(size_t)r * NN + idx] = v;
  }
}

// ---------- init coarse-bucket cursors from CSR offsets ----------
__global__ __launch_bounds__(256)
void k_initg(const int* __restrict__ off, int* __restrict__ gcur) {
  const int i = blockIdx.x * 256 + threadIdx.x;
  if (i < RR * NB) {
    const int r = i / NB, b = i % NB;
    gcur[i] = off[(size_t)r * (NN + 1) + (b << 10)];
  }
}

// ---------- pass 3a: coarse binning with LDS-staged dense writes ----------
__global__ __launch_bounds__(256)
void k_bin(const int* __restrict__ src, const int* __restrict__ dst,
           int* __restrict__ gcur, int2* __restrict__ pairs) {
  const int r = blockIdx.y;
  const long base = (long)blockIdx.x * CHUNK;
  const int t = threadIdx.x;
  __shared__ int hist[NB], lofs[NB], gbase[NB], hcur[NB];
  __shared__ int2 stage[CHUNK];  // 16 KB
  for (int i = t; i < NB; i += 256) hist[i] = 0;
  __syncthreads();
  int d[8], s[8];
#pragma unroll
  for (int k = 0; k < 8; ++k) {
    const long e = base + k * 256 + t;
    if (e < EE) {
      d[k] = dst[(size_t)r * EE + e];
      s[k] = src[(size_t)r * EE + e];
      atomicAdd(&hist[d[k] >> 10], 1);
    } else d[k] = -1;
  }
  __syncthreads();
  if (t == 0) {
    int run = 0;
    for (int b = 0; b < NB; ++b) { lofs[b] = run; run += hist[b]; }
  }
  __syncthreads();
  if (t < NB) {
    hcur[t] = 0;
    gbase[t] = hist[t] ? atomicAdd(&gcur[r * NB + t], hist[t]) : 0;
  }
  __syncthreads();
#pragma unroll
  for (int k = 0; k < 8; ++k) {
    if (d[k] >= 0) {
      const int b = d[k] >> 10;
      const int slot = lofs[b] + atomicAdd(&hcur[b], 1);
      stage[slot] = make_int2(d[k], s[k]);
    }
  }
  __syncthreads();
  const int total = (int)((EE - base < CHUNK) ? (EE - base) : CHUNK);
  for (int i = t; i < total; i += 256) {
    const int2 p = stage[i];
    const int b = p.x >> 10;
    pairs[(size_t)r * EE + gbase[b] + (i - lofs[b])] = p;
  }
}

// ---------- pass 3b: exact placement within L2-resident bucket window ----------
__global__ __launch_bounds__(256)
void k_place(const int2* __restrict__ pairs, const int* __restrict__ off,
             int* __restrict__ cursor, int* __restrict__ sorted) {
  const int r = blockIdx.y;
  const int b = blockIdx.x;
  const int nlo = b << 10;
  const int nhi = (nlo + 1024 < NN) ? nlo + 1024 : NN;
  const int span0 = off[(size_t)r * (NN + 1) + nlo];
  const int span1 = off[(size_t)r * (NN + 1) + nhi];
  for (int i = span0 + threadIdx.x; i < span1; i += 256) {
    const int2 p = pairs[(size_t)r * EE + i];
    const int pos = atomicAdd(&cursor[(size_t)r * NN + p.x], 1);
    sorted[(size_t)r * EE + pos] = p.y;
  }
}

// ---------- convert one relation's features to packed bf16 rows ----------
// nf16[n*64 + lane] holds dims {2*lane, 2*lane+1} of node n as bf16x2.
__global__ __launch_bounds__(256)
void k_cvt(const float* __restrict__ nf, u32* __restrict__ nf16, int r) {
  const long t = (long)blockIdx.x * 256 + threadIdx.x;
  if (t >= (long)NN * 64) return;
  const int n = (int)(t >> 6);
  const int l = (int)(t & 63);
  const float2 v = *(const float2*)(nf + ((size_t)n * RR + r) * DD + l * 2);
  nf16[t] = pack2(v.x, v.y);
}

// ---- copy one 64-row half of a 128x128 f32 weight into LDS ----
__device__ __forceinline__ void loadWh(const float* __restrict__ Wsrc, int half,
                                       float* __restrict__ sW, int tid) {
  const float4* src = (const float4*)(Wsrc + (size_t)half * 64 * DD);
  float4* dstv = (float4*)sW;
#pragma unroll
  for (int k = 0; k < 8; ++k) dstv[tid + k * BLK] = src[tid + k * BLK];  // 2048 float4
}

// ---- 4x4-blocked half-K gemm ----
__device__ __forceinline__ void gemm4x4(const float (*__restrict__ in)[DD],
                                        const float* __restrict__ sW,
                                        int rg, int c4, int kbase, float acc[4][4]) {
  for (int k4 = 0; k4 < 64; k4 += 4) {
    const float4 a0 = *(const float4*)(&in[rg + 0][kbase + k4]);
    const float4 a1 = *(const float4*)(&in[rg + 1][kbase + k4]);
    const float4 a2 = *(const float4*)(&in[rg + 2][kbase + k4]);
    const float4 a3 = *(const float4*)(&in[rg + 3][kbase + k4]);
    const float4 w0 = *(const float4*)(&sW[(k4 + 0) * DD + c4]);
    const float4 w1 = *(const float4*)(&sW[(k4 + 1) * DD + c4]);
    const float4 w2 = *(const float4*)(&sW[(k4 + 2) * DD + c4]);
    const float4 w3 = *(const float4*)(&sW[(k4 + 3) * DD + c4]);
#define ROWF(i, ai)                                                                               \
    acc[i][0] = fmaf(ai.x, w0.x, fmaf(ai.y, w1.x, fmaf(ai.z, w2.x, fmaf(ai.w, w3.x, acc[i][0])))); \
    acc[i][1] = fmaf(ai.x, w0.y, fmaf(ai.y, w1.y, fmaf(ai.z, w2.y, fmaf(ai.w, w3.y, acc[i][1])))); \
    acc[i][2] = fmaf(ai.x, w0.z, fmaf(ai.y, w1.z, fmaf(ai.z, w2.z, fmaf(ai.w, w3.z, acc[i][2])))); \
    acc[i][3] = fmaf(ai.x, w0.w, fmaf(ai.y, w1.w, fmaf(ai.z, w2.w, fmaf(ai.w, w3.w, acc[i][3]))));
    ROWF(0, a0) ROWF(1, a1) ROWF(2, a2) ROWF(3, a3)
#undef ROWF
  }
}

// ------- fused: bf16 gather(CSR) + residual + MLP + LN + attention scores -------
__global__ __launch_bounds__(BLK)
void k_mlp(const float* __restrict__ nf, const u32* __restrict__ nf16,
           const float* __restrict__ W1, const float* __restrict__ b1,
           const float* __restrict__ W2, const float* __restrict__ b2,
           const float* __restrict__ Ws1, const float* __restrict__ Ws2,
           const float* __restrict__ gamma, const float* __restrict__ beta,
           const int* __restrict__ off, const int* __restrict__ sortedSrc,
           float* __restrict__ S, float* __restrict__ out, int r) {
  __shared__ float sA[TN][DD];                 // 16 KB
  __shared__ __align__(16) float sW[64 * DD];  // 32 KB  (total 48 KB)

  const int tid = threadIdx.x;
  const int n0 = blockIdx.x * TN;
  const int rg = (tid >> 5) * 4;   // 8 row groups of 4
  const int c4 = (tid & 31) * 4;   // 32 col groups of 4

  // ---- stage rst = feat(f32) + bf16-gather(CSR) -> sA; wave owns 8 rows ----
  {
    const int wv = tid >> 6;
    const int lane = tid & 63;
    const int* ss = sortedSrc + (size_t)r * EE;
#pragma unroll
    for (int q = 0; q < 8; ++q) {
      const int i = wv * 8 + q;
      const int n = n0 + i;
      float2 a2 = make_float2(0.f, 0.f);
      if (n < NN) {
        a2 = *(const float2*)(nf + ((size_t)n * RR + r) * DD + lane * 2);
        const int e1 = off[(size_t)r * (NN + 1) + n + 1];
        int e = off[(size_t)r * (NN + 1) + n];
        for (; e + 7 < e1; e += 8) {  // unroll-8: 8 bf16 rows in flight
          u32 v[8];
#pragma unroll
          for (int k = 0; k < 8; ++k)
            v[k] = nf16[((size_t)ss[e + k] << 6) + lane];
#pragma unroll
          for (int k = 0; k < 8; ++k) {
            a2.x += u2f(v[k] << 16);
            a2.y += u2f(v[k] & 0xffff0000u);
          }
        }
        for (; e < e1; ++e) {
          const u32 v = nf16[((size_t)ss[e] << 6) + lane];
          a2.x += u2f(v << 16);
          a2.y += u2f(v & 0xffff0000u);
        }
      }
      *(float2*)(&sA[i][lane * 2]) = a2;
    }
  }
  loadWh(W1, 0, sW, tid);
  __syncthreads();

  float acc[4][4];
#pragma unroll
  for (int i = 0; i < 4; ++i)
#pragma unroll
    for (int jj = 0; jj < 4; ++jj) acc[i][jj] = 0.f;

  // ---- GEMM1 ----
  gemm4x4(sA, sW, rg, c4, 0, acc);
  __syncthreads();
  loadWh(W1, 1, sW, tid);
  __syncthreads();
  gemm4x4(sA, sW, rg, c4, 64, acc);
  __syncthreads();
  {
    const float4 bb = *(const float4*)(&b1[c4]);
#pragma unroll
    for (int i = 0; i < 4; ++i)
      *(float4*)(&sA[rg + i][c4]) = make_float4(
          fmaxf(acc[i][0] + bb.x, 0.f), fmaxf(acc[i][1] + bb.y, 0.f),
          fmaxf(acc[i][2] + bb.z, 0.f), fmaxf(acc[i][3] + bb.w, 0.f));
  }
  loadWh(W2, 0, sW, tid);
  __syncthreads();

  // ---- GEMM2 ----
#pragma unroll
  for (int i = 0; i < 4; ++i)
#pragma unroll
    for (int jj = 0; jj < 4; ++jj) acc[i][jj] = 0.f;
  gemm4x4(sA, sW, rg, c4, 0, acc);
  __syncthreads();
  loadWh(W2, 1, sW, tid);
  __syncthreads();
  gemm4x4(sA, sW, rg, c4, 64, acc);
  __syncthreads();
  {
    const float4 bb = *(const float4*)(&b2[c4]);
#pragma unroll
    for (int i = 0; i < 4; ++i)
      *(float4*)(&sA[rg + i][c4]) = make_float4(
          fmaxf(acc[i][0] + bb.x, 0.f), fmaxf(acc[i][1] + bb.y, 0.f),
          fmaxf(acc[i][2] + bb.z, 0.f), fmaxf(acc[i][3] + bb.w, 0.f));
  }
  loadWh(Ws1 + (size_t)r * DD * DD, 0, sW, tid);
  __syncthreads();

  // ---- LayerNorm (8 threads/row, stats in registers via shfl) ----
  {
    const int i = tid >> 3;          // 0..31
    const int c0 = (tid & 7) * 16;
    float s = 0.f, s2 = 0.f;
    float hv[16];
#pragma unroll
    for (int c = 0; c < 16; ++c) {
      const float v = sA[i][c0 + c];
      hv[c] = v;
      s += v; s2 += v * v;
    }
#pragma unroll
    for (int off2 = 1; off2 < 8; off2 <<= 1) {
      s  += __shfl_xor(s, off2);
      s2 += __shfl_xor(s2, off2);
    }
    const float mu = s * (1.f / 128.f);
    const float var = fmaxf(s2 * (1.f / 128.f) - mu * mu, 0.f);
    const float rs = rsqrtf(var + 1e-5f);
    const int n = n0 + i;
#pragma unroll
    for (int c = 0; c < 16; ++c) {
      hv[c] = (hv[c] - mu) * rs * gamma[c0 + c] + beta[c0 + c];
      sA[i][c0 + c] = hv[c];   // own slice only: no cross-thread hazard
    }
    if (n < NN) {
      float4* op = (float4*)(out + ((size_t)n * RR + r) * DD + c0);
#pragma unroll
      for (int q = 0; q < 4; ++q)
        op[q] = make_float4(hv[q * 4], hv[q * 4 + 1], hv[q * 4 + 2], hv[q * 4 + 3]);
    }
  }
  __syncthreads();

  // ---- GEMM3: tanh(h @ Ws1[r]) ----
#pragma unroll
  for (int i = 0; i < 4; ++i)
#pragma unroll
    for (int jj = 0; jj < 4; ++jj) acc[i][jj] = 0.f;
  gemm4x4(sA, sW, rg, c4, 0, acc);
  __syncthreads();
  loadWh(Ws1 + (size_t)r * DD * DD, 1, sW, tid);
  __syncthreads();
  gemm4x4(sA, sW, rg, c4, 64, acc);
  __syncthreads();
#pragma unroll
  for (int i = 0; i < 4; ++i)
    *(float4*)(&sA[rg + i][c4]) = make_float4(
        tanhf(acc[i][0]), tanhf(acc[i][1]), tanhf(acc[i][2]), tanhf(acc[i][3]));
  {
    sW[tid]       = Ws2[(size_t)r * 512 + tid];
    sW[tid + 256] = Ws2[(size_t)r * 512 + tid + 256];
  }
  __syncthreads();

  // ---- scores = tanh(...) @ Ws2[r] -> S ----
  if (tid < TN * 4) {
    const int i = tid >> 2;
    const int k = tid & 3;
    float a = 0.f;
#pragma unroll 8
    for (int q = 0; q < DD; ++q) a = fmaf(sA[i][q], sW[q * 4 + k], a);
    const int n = n0 + i;
    if (n < NN) S[((size_t)r * NN + n) * 4 + k] = a;
  }
}

// -------- softmax over relations + final mix (in place on out) --------
__global__ __launch_bounds__(256)
void k_combine(const float* __restrict__ S, float* __restrict__ out) {
  const long gw = (((long)blockIdx.x * 256) + threadIdx.x) >> 6;
  const int lane = threadIdx.x & 63;
  if (gw >= NN) return;
  const int n = (int)gw;
  float a[4][4];
#pragma unroll
  for (int r = 0; r < 4; ++r)
#pragma unroll
    for (int k = 0; k < 4; ++k)
      a[r][k] = S[((size_t)r * NN + n) * 4 + k];
#pragma unroll
  for (int k = 0; k < 4; ++k) {
    const float m = fmaxf(fmaxf(a[0][k], a[1][k]), fmaxf(a[2][k], a[3][k]));
    const float e0 = expf(a[0][k] - m);
    const float e1 = expf(a[1][k] - m);
    const float e2 = expf(a[2][k] - m);
    const float e3 = expf(a[3][k] - m);
    const float inv = 1.f / (e0 + e1 + e2 + e3);
    a[0][k] = e0 * inv; a[1][k] = e1 * inv; a[2][k] = e2 * inv; a[3][k] = e3 * inv;
  }
  float2 hv[4];
#pragma unroll
  for (int k = 0; k < 4; ++k)
    hv[k] = *(const float2*)(out + ((size_t)n * RR + k) * DD + lane * 2);
#pragma unroll
  for (int r = 0; r < 4; ++r) {
    float2 o;
    o.x = a[r][0] * hv[0].x + a[r][1] * hv[1].x + a[r][2] * hv[2].x + a[r][3] * hv[3].x;
    o.y = a[r][0] * hv[0].y + a[r][1] * hv[1].y + a[r][2] * hv[2].y + a[r][3] * hv[3].y;
    *(float2*)(out + ((size_t)n * RR + r) * DD + lane * 2) = o;
  }
}

extern "C" void kernel_launch(void* const* d_in, const int* in_sizes, int n_in,
                              void* d_out, int out_size, void* d_ws, size_t ws_size,
                              hipStream_t stream) {
  const float* nf    = (const float*)d_in[0];
  const int*   src   = (const int*)d_in[1];
  const int*   dst   = (const int*)d_in[2];
  const float* W1    = (const float*)d_in[3];
  const float* b1    = (const float*)d_in[4];
  const float* W2    = (const float*)d_in[5];
  const float* b2    = (const float*)d_in[6];
  const float* Ws1   = (const float*)d_in[7];
  const float* Ws2   = (const float*)d_in[8];
  const float* gamma = (const float*)d_in[9];
  const float* beta  = (const float*)d_in[10];
  float* out = (float*)d_out;

  // ws layout (~114 MB):
  //   S      : RR*NN*4 f32   (6.4 MB)
  //   off    : RR*(NN+1) int (1.6 MB)   CSR offsets
  //   cursor : RR*NN int     (1.6 MB)   node fill cursors
  //   bsum   : RR*NB int                scan block sums
  //   gcur   : RR*NB int                coarse-bucket cursors
  //   pairs  : RR*EE int2    (51.2 MB)  coarse-binned (dst,src)
  //   sorted : RR*EE int     (25.6 MB)  src grouped by dst
  //   nf16   : NN*64 u32     (25.6 MB)  current relation's bf16x2 rows
  float* S      = (float*)d_ws;
  int*   off    = (int*)(S + (size_t)RR * NN * 4);
  int*   cursor = off + (size_t)RR * (NN + 1);
  int*   bsum   = cursor + (size_t)RR * NN;
  int*   gcur   = bsum + (size_t)RR * NB;
  int2*  pairs  = (int2*)(gcur + (size_t)RR * NB);
  int*   sorted = (int*)(pairs + (size_t)RR * EE);
  u32*   nf16   = (u32*)(sorted + (size_t)RR * EE);

  hipMemsetAsync(off, 0, (size_t)RR * (NN + 1) * sizeof(int), stream);
  {
    dim3 grid((EE + 255) / 256, RR);
    k_hist<<<grid, dim3(256), 0, stream>>>(dst, off);
  }
  k_scan1<<<dim3(NB, RR), dim3(1024), 0, stream>>>(off, bsum);
  k_scan2<<<dim3(RR), dim3(128), 0, stream>>>(bsum);
  k_scan3<<<dim3(NB, RR), dim3(1024), 0, stream>>>(off, bsum, cursor);
  k_initg<<<dim3((RR * NB + 255) / 256), dim3(256), 0, stream>>>(off, gcur);
  {
    dim3 grid((EE + CHUNK - 1) / CHUNK, RR);
    k_bin<<<grid, dim3(256), 0, stream>>>(src, dst, gcur, pairs);
  }
  k_place<<<dim3(NB, RR), dim3(256), 0, stream>>>(pairs, off, cursor, sorted);
  for (int r = 0; r < RR; ++r) {
    k_cvt<<<dim3((unsigned)(((long)NN * 64 + 255) / 256)), dim3(256), 0, stream>>>(nf, nf16, r);
    dim3 grid((NN + TN - 1) / TN);
    k_mlp<<<grid, dim3(BLK), 0, stream>>>(nf, nf16, W1, b1, W2, b2, Ws1, Ws2,
                                          gamma, beta, off, sorted, S, out, r);
  }
  {
    const long blocks = ((long)NN + 3) / 4;  // 1 wave/node
    k_combine<<<dim3((unsigned)blocks), dim3(256), 0, stream>>>(S, out);
  }
}